// Round 12
// baseline (685.884 us; speedup 1.0000x reference)
//
#include <hip/hip_runtime.h>
#include <hip/hip_bf16.h>
#include <hip/hip_cooperative_groups.h>

namespace cg = cooperative_groups;

#define NN 50000
#define EE 800000
#define FIN 500
#define H1D 300
#define H2D 100
#define CC 16
#define GNB 196          // (NN+255)/256
#define PREP_N1 196608   // 384*512
#define PREP_N2 40960    // 128*320
#define PREP_BLOCKS 928  // (PREP_N1+PREP_N2)/256

// ---------- dtype-flexible load helpers ----------
__device__ __forceinline__ float ldf(const void* p, size_t i, int isbf16) {
    return isbf16 ? __bfloat162float(((const __hip_bfloat16*)p)[i])
                  : ((const float*)p)[i];
}
__device__ __forceinline__ int ld_src(const int* ei, int e, int is64) {
    return is64 ? ei[2 * (size_t)e] : ei[e];
}
__device__ __forceinline__ int ld_dst(const int* ei, int e, int is64) {
    return is64 ? ei[2 * ((size_t)EE + e)] : ei[(size_t)EE + e];
}

// split fp32 -> hi/lo bf16 (hi+lo captures ~17 mantissa bits)
__device__ __forceinline__ void split2(float f, unsigned short& h, unsigned short& l) {
    __bf16 hb = (__bf16)f;
    float fh = (float)hb;
    __bf16 lb = (__bf16)(f - fh);
    h = __builtin_bit_cast(unsigned short, hb);
    l = __builtin_bit_cast(unsigned short, lb);
}

// unpack 2 packed bf16 to float2
__device__ __forceinline__ float2 bf2f2(unsigned int v) {
    float lo = __builtin_bit_cast(float, v << 16);
    float hi = __builtin_bit_cast(float, v & 0xffff0000u);
    return make_float2(lo, hi);
}

typedef __bf16 bf16x8 __attribute__((ext_vector_type(8)));
typedef float f32x4 __attribute__((ext_vector_type(4)));

// ---------- prep body ----------
__device__ __forceinline__ void prep_body(int idx, const float* linW, const float* W1,
                                          unsigned short* Bt1, unsigned short* Bt2) {
    if (idx < PREP_N1) {
        int n = idx >> 9, k = idx & 511;
        float v = (n < H1D && k < FIN) ? linW[(size_t)k * H1D + n] : 0.0f;
        unsigned short h, l;
        split2(v, h, l);
        Bt1[(size_t)n * 1024 + k] = h;
        Bt1[(size_t)n * 1024 + 512 + k] = l;
    } else if (idx < PREP_N1 + PREP_N2) {
        idx -= PREP_N1;
        int n = idx / 320, k = idx - n * 320;
        float v = (n < H2D && k < H1D) ? W1[(size_t)k * H2D + n] : 0.0f;
        unsigned short h, l;
        split2(v, h, l);
        Bt2[(size_t)n * 640 + k] = h;
        Bt2[(size_t)n * 640 + 320 + k] = l;
    }
}

// ---------- init: sniff (block 0) + optional weight prep (blocks 1..) ----------
__global__ __launch_bounds__(256) void k_init(const unsigned short* __restrict__ xw,
                                              const unsigned int* __restrict__ ew,
                                              int* __restrict__ flags,
                                              const float* __restrict__ linW,
                                              const float* __restrict__ W1,
                                              unsigned short* __restrict__ Bt1,
                                              unsigned short* __restrict__ Bt2) {
    int b = blockIdx.x;
    if (b == 0) {
        __shared__ int c_sane, c_zero;
        if (threadIdx.x == 0) { c_sane = 0; c_zero = 0; }
        __syncthreads();
        int t = threadIdx.x;
        int sane = 0, zer = 0;
        for (int j = 0; j < 4; j++) {
            unsigned short w = xw[t * 4 + j];
            int ex = (w >> 7) & 0xFF;
            if (w == 0 || (ex >= 100 && ex <= 150)) sane++;
            if (ew[2 * (t * 4 + j) + 1] == 0u) zer++;
        }
        atomicAdd(&c_sane, sane);
        atomicAdd(&c_zero, zer);
        __syncthreads();
        if (threadIdx.x == 0) {
            flags[0] = (c_sane > 820) ? 1 : 0;
            flags[1] = (c_zero > 512) ? 1 : 0;
        }
    } else {
        // only present when host is CERTAIN input is fp32 (grid extended)
        prep_body((b - 1) * 256 + threadIdx.x, linW, W1, Bt1, Bt2);
    }
}

// standalone prep for the uncertain-dtype path (flags-gated)
__global__ __launch_bounds__(256) void k_prep_both(const float* __restrict__ linW,
                                                   const float* __restrict__ W1,
                                                   unsigned short* __restrict__ Bt1,
                                                   unsigned short* __restrict__ Bt2,
                                                   const int* __restrict__ flags) {
    if (flags[0]) return;
    prep_body(blockIdx.x * 256 + threadIdx.x, linW, W1, Bt1, Bt2);
}

// ---------- cooperative CSR build: zero + hist + scan/dinv + scatter in ONE launch ----------
// Replaces 4 dependent dispatches (3 inter-kernel drains + gaps removed).
// Row regions non-monotone across scan chunks (legal: agg uses lo + deg).
__global__ __launch_bounds__(256) void k_csr_coop(const int* __restrict__ ei,
                                                  int* __restrict__ cnt,
                                                  int* __restrict__ row_ptr,
                                                  float* __restrict__ dinv,
                                                  int* __restrict__ csr_src,
                                                  int* __restrict__ total,
                                                  const int* __restrict__ flags) {
    cg::grid_group grid = cg::this_grid();
    const int T = gridDim.x * blockDim.x;
    const int gtid = blockIdx.x * blockDim.x + threadIdx.x;
    // P0: zero counters
    for (int i = gtid; i < NN; i += T) cnt[i] = 0;
    if (gtid == 0) total[0] = 0;
    grid.sync();
    // P1: degree histogram
    const int is64 = flags[1];
    for (int e = gtid; e < EE; e += T) {
        int d = ld_dst(ei, e, is64);
        if ((unsigned)d < NN) atomicAdd(&cnt[d], 1);
    }
    grid.sync();
    // P2: per-chunk scan + atomic base; dinv fused; cnt reset as scatter fill
    if (blockIdx.x < GNB) {
        int t = threadIdx.x;
        int i = blockIdx.x * 256 + t;
        int c = (i < NN) ? cnt[i] : 0;
        __shared__ int s[256];
        s[t] = c;
        __syncthreads();
        for (int off2 = 1; off2 < 256; off2 <<= 1) {
            int v = (t >= off2) ? s[t - off2] : 0;
            __syncthreads();
            s[t] += v;
            __syncthreads();
        }
        __shared__ int base;
        if (t == 255) base = atomicAdd(total, s[255]);
        __syncthreads();
        if (i < NN) {
            row_ptr[i] = base + s[t] - c;
            dinv[i] = rsqrtf((float)c + 1.0f);  // +1 self loop
            cnt[i] = 0;
        }
    }
    grid.sync();
    // P3: scatter (cnt becomes deg when done)
    for (int e = gtid; e < EE; e += T) {
        int sv = ld_src(ei, e, is64);
        int d = ld_dst(ei, e, is64);
        if ((unsigned)d < NN) {
            int pos = row_ptr[d] + atomicAdd(&cnt[d], 1);
            csr_src[pos] = sv;
        }
    }
}

// ---------- non-cooperative fallback chain ----------
__global__ void k_zero_cnt(int* __restrict__ cnt, int* __restrict__ total) {
    int i = blockIdx.x * blockDim.x + threadIdx.x;
    if (i < NN) cnt[i] = 0;
    if (i == 0) total[0] = 0;
}
__global__ void k_hist(const int* __restrict__ ei, int* __restrict__ cnt,
                       const int* __restrict__ flags) {
    int e = blockIdx.x * blockDim.x + threadIdx.x;
    int is64 = flags[1];
    if (e < EE) {
        int d = ld_dst(ei, e, is64);
        if ((unsigned)d < NN) atomicAdd(&cnt[d], 1);
    }
}
__global__ __launch_bounds__(256) void k_scan_mb(int* __restrict__ cnt,
                                                 int* __restrict__ row_ptr,
                                                 float* __restrict__ dinv,
                                                 int* __restrict__ total) {
    int t = threadIdx.x;
    int i = blockIdx.x * 256 + t;
    int c = (i < NN) ? cnt[i] : 0;
    __shared__ int s[256];
    s[t] = c;
    __syncthreads();
    for (int off = 1; off < 256; off <<= 1) {
        int v = (t >= off) ? s[t - off] : 0;
        __syncthreads();
        s[t] += v;
        __syncthreads();
    }
    __shared__ int base;
    if (t == 255) base = atomicAdd(total, s[255]);
    __syncthreads();
    if (i < NN) {
        row_ptr[i] = base + s[t] - c;
        dinv[i] = rsqrtf((float)c + 1.0f);
        cnt[i] = 0;
    }
}
__global__ void k_scatter(const int* __restrict__ ei, const int* __restrict__ row_ptr,
                          int* __restrict__ fill, int* __restrict__ csr_src,
                          const int* __restrict__ flags) {
    int e = blockIdx.x * blockDim.x + threadIdx.x;
    int is64 = flags[1];
    if (e < EE) {
        int s = ld_src(ei, e, is64);
        int d = ld_dst(ei, e, is64);
        if ((unsigned)d < NN) {
            int pos = row_ptr[d] + atomicAdd(&fill[d], 1);
            csr_src[pos] = s;
        }
    }
}

// ---------- bf16-input fallback tiled GEMM (runs only when flags[0]==1) ----------
template <bool A_DYN, bool RELU, bool SCALE, bool OUTBF>
__global__ __launch_bounds__(256) void k_gemm(const void* __restrict__ A,
                                              const void* __restrict__ B,
                                              const void* __restrict__ bias,
                                              const float* __restrict__ dinv,
                                              void* __restrict__ C,
                                              int M, int K, int Nn,
                                              const int* __restrict__ flags) {
    if (!flags[0]) return;
    __shared__ float As[16][68];
    __shared__ float Bs[16][68];
    const int bf = flags[0];
    const int tid = threadIdx.x;
    const int m0 = blockIdx.x * 64, n0 = blockIdx.y * 64;
    const int tx = tid & 15;
    const int ty = tid >> 4;
    float acc[4][4] = {};

    for (int kc = 0; kc < K; kc += 16) {
#pragma unroll
        for (int j = 0; j < 4; j++) {
            int idx = tid + j * 256;
            int kk = idx & 15, mm = idx >> 4;
            int gm = m0 + mm, gk = kc + kk;
            float v = 0.0f;
            if (gm < M && gk < K) {
                size_t o = (size_t)gm * K + gk;
                v = A_DYN ? ldf(A, o, bf) : ((const float*)A)[o];
            }
            As[kk][mm] = v;
        }
#pragma unroll
        for (int j = 0; j < 4; j++) {
            int idx = tid + j * 256;
            int nn = idx & 63, kk = idx >> 6;
            int gk = kc + kk, gn = n0 + nn;
            Bs[kk][nn] = (gk < K && gn < Nn) ? ldf(B, (size_t)gk * Nn + gn, bf) : 0.0f;
        }
        __syncthreads();
#pragma unroll
        for (int kk = 0; kk < 16; kk++) {
            float4 a4 = *(const float4*)&As[kk][ty * 4];
            float4 b4 = *(const float4*)&Bs[kk][tx * 4];
            float av[4] = {a4.x, a4.y, a4.z, a4.w};
            float bv[4] = {b4.x, b4.y, b4.z, b4.w};
#pragma unroll
            for (int i = 0; i < 4; i++)
#pragma unroll
                for (int j = 0; j < 4; j++) acc[i][j] += av[i] * bv[j];
        }
        __syncthreads();
    }

#pragma unroll
    for (int i = 0; i < 4; i++) {
        int m = m0 + ty * 4 + i;
        if (m >= M) continue;
        float sc = SCALE ? dinv[m] : 1.0f;
#pragma unroll
        for (int j = 0; j < 4; j++) {
            int n = n0 + tx * 4 + j;
            if (n >= Nn) continue;
            float v = acc[i][j];
            if (bias) v += ldf(bias, n, bf);
            if (SCALE) v *= sc;
            if (RELU) v = fmaxf(v, 0.0f);
            if (OUTBF) ((__hip_bfloat16*)C)[(size_t)m * Nn + n] = __float2bfloat16(v);
            else       ((float*)C)[(size_t)m * Nn + n] = v;
        }
    }
}

// ---------- split-bf16 MFMA GEMM1 (R7/R10-proven K-loop; single dispatch) ----------
template <int BM, int WN, bool RELU, bool SCALE, bool HAS_BIAS, bool OUTBF>
__global__ __launch_bounds__(256) void k_gemm_mfma_split(const float* __restrict__ A,
                                                         const unsigned short* __restrict__ Bt,
                                                         const float* __restrict__ bias,
                                                         const float* __restrict__ dinv,
                                                         void* __restrict__ C,
                                                         int M, int K, int Kp, int Nn, int NnS,
                                                         const int* __restrict__ flags) {
    if (flags[0]) return;
    constexpr int WM = 4 / WN;
    constexpr int FM = BM / WM / 16;
    constexpr int FN = 128 / WN / 16;
    constexpr int NA = BM / 32;
    __shared__ unsigned short As_hi[BM * 32], As_lo[BM * 32];
    __shared__ unsigned short Bs_hi[4096], Bs_lo[4096];
    const int tid = threadIdx.x;
    const int nbx = gridDim.x;
    const int Wt = nbx * gridDim.y;
    const int li = blockIdx.x + nbx * blockIdx.y;
    const int q8 = Wt >> 3, r8 = Wt & 7;
    const int xk = li & 7, xj = li >> 3;
    const int wid = (xk < r8 ? xk * (q8 + 1) : r8 * (q8 + 1) + (xk - r8) * q8) + xj;
    const int n0 = (wid % nbx) * 128;
    const int m0 = (wid / nbx) * BM;
    const int w = tid >> 6, l = tid & 63;
    const int wm = (w / WN) * (BM / WM);
    const int wn = (w % WN) * (128 / WN);
    const int lr = l & 15, ls = l >> 4;
    f32x4 acc[FM][FN] = {};

    float4 stA[NA];
    uint4  stB0, stB1, stB2, stB3;

#define LOAD_TILE(kc_)                                                              \
    {                                                                               \
        int kc = (kc_);                                                             \
        _Pragma("unroll")                                                           \
        for (int j = 0; j < NA; j++) {                                              \
            int c = tid + j * 256;                                                  \
            int r = c >> 3, q = c & 7;                                              \
            int gm = m0 + r, gk = kc + q * 4;                                       \
            stA[j] = (gm < M && gk < K) ? *(const float4*)(A + (size_t)gm * K + gk) \
                                        : make_float4(0.f, 0.f, 0.f, 0.f);          \
        }                                                                           \
        {                                                                           \
            int c, r, q, gn;                                                        \
            c = tid;       r = c >> 2; q = c & 3; gn = n0 + r;                      \
            stB0 = *(const uint4*)(Bt + (size_t)gn * (2 * Kp) + kc + q * 8);        \
            c = tid + 256; r = c >> 2; q = c & 3; gn = n0 + r;                      \
            stB1 = *(const uint4*)(Bt + (size_t)gn * (2 * Kp) + kc + q * 8);        \
            c = tid;       r = c >> 2; q = c & 3; gn = n0 + r;                      \
            stB2 = *(const uint4*)(Bt + (size_t)gn * (2 * Kp) + Kp + kc + q * 8);   \
            c = tid + 256; r = c >> 2; q = c & 3; gn = n0 + r;                      \
            stB3 = *(const uint4*)(Bt + (size_t)gn * (2 * Kp) + Kp + kc + q * 8);   \
        }                                                                           \
    }

#define WRITE_TILE()                                                                \
    {                                                                               \
        _Pragma("unroll")                                                           \
        for (int j = 0; j < NA; j++) {                                              \
            int c = tid + j * 256;                                                  \
            int r = c >> 3, q = c & 7;                                              \
            unsigned short h0,h1,h2,h3,l0,l1,l2,l3;                                 \
            split2(stA[j].x, h0, l0); split2(stA[j].y, h1, l1);                     \
            split2(stA[j].z, h2, l2); split2(stA[j].w, h3, l3);                     \
            int waddr = r * 64 + (((q >> 1) ^ ((r >> 1) & 3)) << 4) + ((q & 1) << 3); \
            *(ushort4*)((char*)As_hi + waddr) = make_ushort4(h0, h1, h2, h3);       \
            *(ushort4*)((char*)As_lo + waddr) = make_ushort4(l0, l1, l2, l3);       \
        }                                                                           \
        {                                                                           \
            int c, r, q, waddr;                                                     \
            c = tid;       r = c >> 2; q = c & 3; waddr = r * 64 + ((q ^ ((r >> 1) & 3)) << 4); \
            *(uint4*)((char*)Bs_hi + waddr) = stB0;                                 \
            c = tid + 256; r = c >> 2; q = c & 3; waddr = r * 64 + ((q ^ ((r >> 1) & 3)) << 4); \
            *(uint4*)((char*)Bs_hi + waddr) = stB1;                                 \
            c = tid;       r = c >> 2; q = c & 3; waddr = r * 64 + ((q ^ ((r >> 1) & 3)) << 4); \
            *(uint4*)((char*)Bs_lo + waddr) = stB2;                                 \
            c = tid + 256; r = c >> 2; q = c & 3; waddr = r * 64 + ((q ^ ((r >> 1) & 3)) << 4); \
            *(uint4*)((char*)Bs_lo + waddr) = stB3;                                 \
        }                                                                           \
    }

    const int nsteps = (K + 31) / 32;
    LOAD_TILE(0);
    for (int kt = 0; kt < nsteps; kt++) {
        WRITE_TILE();
        __syncthreads();
        if (kt + 1 < nsteps) LOAD_TILE((kt + 1) * 32);
        bf16x8 ah[FM], al[FM], bh[FN], bl[FN];
#pragma unroll
        for (int fm = 0; fm < FM; fm++) {
            int rr = wm + fm * 16 + lr;
            int addr = rr * 64 + ((ls ^ ((rr >> 1) & 3)) << 4);
            ah[fm] = *(const bf16x8*)((const char*)As_hi + addr);
            al[fm] = *(const bf16x8*)((const char*)As_lo + addr);
        }
#pragma unroll
        for (int fn = 0; fn < FN; fn++) {
            int cc2 = wn + fn * 16 + lr;
            int addr = cc2 * 64 + ((ls ^ ((cc2 >> 1) & 3)) << 4);
            bh[fn] = *(const bf16x8*)((const char*)Bs_hi + addr);
            bl[fn] = *(const bf16x8*)((const char*)Bs_lo + addr);
        }
#pragma unroll
        for (int fm = 0; fm < FM; fm++)
#pragma unroll
            for (int fn = 0; fn < FN; fn++) {
                acc[fm][fn] = __builtin_amdgcn_mfma_f32_16x16x32_bf16(ah[fm], bh[fn], acc[fm][fn], 0, 0, 0);
                acc[fm][fn] = __builtin_amdgcn_mfma_f32_16x16x32_bf16(ah[fm], bl[fn], acc[fm][fn], 0, 0, 0);
                acc[fm][fn] = __builtin_amdgcn_mfma_f32_16x16x32_bf16(al[fm], bh[fn], acc[fm][fn], 0, 0, 0);
            }
        __syncthreads();
    }
#undef LOAD_TILE
#undef WRITE_TILE

    // epilogue: C/D layout col=lane&15, row=(lane>>4)*4+reg [m89-verified]
#pragma unroll
    for (int fm = 0; fm < FM; fm++) {
#pragma unroll
        for (int j = 0; j < 4; j++) {
            int m = m0 + wm + fm * 16 + ls * 4 + j;
            if (m >= M) continue;
            float sc = SCALE ? dinv[m] : 1.0f;
#pragma unroll
            for (int fn = 0; fn < FN; fn++) {
                int n = n0 + wn + fn * 16 + lr;
                if (OUTBF) {
                    if (n >= NnS) continue;
                    float v = 0.0f;
                    if (n < Nn) {
                        v = acc[fm][fn][j];
                        if (HAS_BIAS) v += bias[n];
                        if (SCALE) v *= sc;
                        if (RELU) v = fmaxf(v, 0.0f);
                    }
                    ((__hip_bfloat16*)C)[(size_t)m * NnS + n] = __float2bfloat16(v);
                } else {
                    if (n >= Nn) continue;
                    float v = acc[fm][fn][j];
                    if (HAS_BIAS) v += bias[n];
                    if (SCALE) v *= sc;
                    if (RELU) v = fmaxf(v, 0.0f);
                    ((float*)C)[(size_t)m * Nn + n] = v;
                }
            }
        }
    }
}

// ---------- GEMM2 with bf16 A: H1p = (H1bf[M][320] @ W1) * dinv -> bf16 [M][100] ----------
__global__ __launch_bounds__(256) void k_gemm2_bf16a(const unsigned short* __restrict__ A,
                                                     const unsigned short* __restrict__ Bt,
                                                     const float* __restrict__ dinv,
                                                     unsigned short* __restrict__ C,
                                                     int M, const int* __restrict__ flags) {
    if (flags[0]) return;
    constexpr int Kp = 320;
    __shared__ unsigned short As[64 * 32];
    __shared__ unsigned short Bs_hi[4096], Bs_lo[4096];
    const int tid = threadIdx.x;
    const int Wt = gridDim.x;
    const int li = blockIdx.x;
    const int q8 = Wt >> 3, r8 = Wt & 7;
    const int xk = li & 7, xj = li >> 3;
    const int wid = (xk < r8 ? xk * (q8 + 1) : r8 * (q8 + 1) + (xk - r8) * q8) + xj;
    const int m0 = wid * 64;
    const int w = tid >> 6, l = tid & 63;
    const int wn = w * 32;
    const int lr = l & 15, ls = l >> 4;
    f32x4 acc[4][2] = {};

    uint4 stA, stB0, stB1, stB2, stB3;

#define LOAD_T2(kc_)                                                                \
    {                                                                               \
        int kc = (kc_);                                                             \
        {                                                                           \
            int r = tid >> 2, q = tid & 3;                                          \
            int gm = m0 + r;                                                        \
            stA = (gm < M) ? *(const uint4*)(A + (size_t)gm * Kp + kc + q * 8)      \
                           : make_uint4(0u, 0u, 0u, 0u);                            \
        }                                                                           \
        {                                                                           \
            int c, r, q, gn;                                                        \
            c = tid;       r = c >> 2; q = c & 3; gn = r;                           \
            stB0 = *(const uint4*)(Bt + (size_t)gn * (2 * Kp) + kc + q * 8);        \
            c = tid + 256; r = c >> 2; q = c & 3; gn = r;                           \
            stB1 = *(const uint4*)(Bt + (size_t)gn * (2 * Kp) + kc + q * 8);        \
            c = tid;       r = c >> 2; q = c & 3; gn = r;                           \
            stB2 = *(const uint4*)(Bt + (size_t)gn * (2 * Kp) + Kp + kc + q * 8);   \
            c = tid + 256; r = c >> 2; q = c & 3; gn = r;                           \
            stB3 = *(const uint4*)(Bt + (size_t)gn * (2 * Kp) + Kp + kc + q * 8);   \
        }                                                                           \
    }

#define WRITE_T2()                                                                  \
    {                                                                               \
        {                                                                           \
            int r = tid >> 2, q = tid & 3;                                          \
            int waddr = r * 64 + ((q ^ ((r >> 1) & 3)) << 4);                       \
            *(uint4*)((char*)As + waddr) = stA;                                     \
        }                                                                           \
        {                                                                           \
            int c, r, q, waddr;                                                     \
            c = tid;       r = c >> 2; q = c & 3; waddr = r * 64 + ((q ^ ((r >> 1) & 3)) << 4); \
            *(uint4*)((char*)Bs_hi + waddr) = stB0;                                 \
            c = tid + 256; r = c >> 2; q = c & 3; waddr = r * 64 + ((q ^ ((r >> 1) & 3)) << 4); \
            *(uint4*)((char*)Bs_hi + waddr) = stB1;                                 \
            c = tid;       r = c >> 2; q = c & 3; waddr = r * 64 + ((q ^ ((r >> 1) & 3)) << 4); \
            *(uint4*)((char*)Bs_lo + waddr) = stB2;                                 \
            c = tid + 256; r = c >> 2; q = c & 3; waddr = r * 64 + ((q ^ ((r >> 1) & 3)) << 4); \
            *(uint4*)((char*)Bs_lo + waddr) = stB3;                                 \
        }                                                                           \
    }

    const int nsteps = Kp / 32;  // 10
    LOAD_T2(0);
    for (int kt = 0; kt < nsteps; kt++) {
        WRITE_T2();
        __syncthreads();
        if (kt + 1 < nsteps) LOAD_T2((kt + 1) * 32);
        bf16x8 ah[4], bh[2], bl[2];
#pragma unroll
        for (int fm = 0; fm < 4; fm++) {
            int rr = fm * 16 + lr;
            int addr = rr * 64 + ((ls ^ ((rr >> 1) & 3)) << 4);
            ah[fm] = *(const bf16x8*)((const char*)As + addr);
        }
#pragma unroll
        for (int fn = 0; fn < 2; fn++) {
            int cc2 = wn + fn * 16 + lr;
            int addr = cc2 * 64 + ((ls ^ ((cc2 >> 1) & 3)) << 4);
            bh[fn] = *(const bf16x8*)((const char*)Bs_hi + addr);
            bl[fn] = *(const bf16x8*)((const char*)Bs_lo + addr);
        }
#pragma unroll
        for (int fm = 0; fm < 4; fm++)
#pragma unroll
            for (int fn = 0; fn < 2; fn++) {
                acc[fm][fn] = __builtin_amdgcn_mfma_f32_16x16x32_bf16(ah[fm], bh[fn], acc[fm][fn], 0, 0, 0);
                acc[fm][fn] = __builtin_amdgcn_mfma_f32_16x16x32_bf16(ah[fm], bl[fn], acc[fm][fn], 0, 0, 0);
            }
        __syncthreads();
    }
#undef LOAD_T2
#undef WRITE_T2

#pragma unroll
    for (int fm = 0; fm < 4; fm++) {
#pragma unroll
        for (int j = 0; j < 4; j++) {
            int m = m0 + fm * 16 + ls * 4 + j;
            if (m >= M) continue;
            float sc = dinv[m];
#pragma unroll
            for (int fn = 0; fn < 2; fn++) {
                int n = wn + fn * 16 + lr;
                if (n >= H2D) continue;
                ((__hip_bfloat16*)C)[(size_t)m * H2D + n] = __float2bfloat16(acc[fm][fn][j] * sc);
            }
        }
    }
}

// ---------- agg1 + gemm3 fused ----------
__global__ __launch_bounds__(256) void k_agg1_fused(const unsigned short* __restrict__ h1p_bf,
                                                    const int* __restrict__ row_ptr,
                                                    const int* __restrict__ deg,
                                                    const int* __restrict__ csr_src,
                                                    const float* __restrict__ dinv,
                                                    const void* __restrict__ b1,
                                                    const void* __restrict__ W2,
                                                    float* __restrict__ h2p,
                                                    const int* __restrict__ flags) {
    __shared__ float W2s[16][105];
    __shared__ float b1s[H2D];
    __shared__ float Hrow[4][H2D];
    const int bf = flags[0];
    const int tid = threadIdx.x;
    for (int i = tid; i < H2D * CC; i += 256) {
        int k = i >> 4, n = i & 15;
        W2s[n][k] = ldf(W2, i, bf);
    }
    for (int i = tid; i < H2D; i += 256) b1s[i] = ldf(b1, i, bf);
    __syncthreads();

    const int w = tid >> 6, lane = tid & 63;
    const int q = lane >> 4, n16 = lane & 15;
    const unsigned int* rows = (const unsigned int*)h1p_bf;  // 50 uints/node
    for (int node = blockIdx.x * 4 + w; node < NN; node += gridDim.x * 4) {
        float di = dinv[node];
        if (lane < 50) {
            float2 s = bf2f2(rows[(size_t)node * 50 + lane]);  // self loop
            float a0x = s.x, a0y = s.y;
            float a1x = 0.f, a1y = 0.f, a2x = 0.f, a2y = 0.f, a3x = 0.f, a3y = 0.f;
            int lo = row_ptr[node], hi = lo + deg[node];
            int e = lo;
            for (; e + 3 < hi; e += 4) {
                int s0 = csr_src[e], s1 = csr_src[e + 1], s2 = csr_src[e + 2], s3 = csr_src[e + 3];
                float2 v0 = bf2f2(rows[(size_t)s0 * 50 + lane]);
                float2 v1 = bf2f2(rows[(size_t)s1 * 50 + lane]);
                float2 v2 = bf2f2(rows[(size_t)s2 * 50 + lane]);
                float2 v3 = bf2f2(rows[(size_t)s3 * 50 + lane]);
                a0x += v0.x; a0y += v0.y;
                a1x += v1.x; a1y += v1.y;
                a2x += v2.x; a2y += v2.y;
                a3x += v3.x; a3y += v3.y;
            }
            for (; e < hi; e++) {
                float2 v = bf2f2(rows[(size_t)csr_src[e] * 50 + lane]);
                a0x += v.x; a0y += v.y;
            }
            float sx = (a0x + a1x) + (a2x + a3x);
            float sy = (a0y + a1y) + (a2y + a3y);
            int f = lane * 2;
            Hrow[w][f]     = fmaxf(sx * di + b1s[f], 0.0f);
            Hrow[w][f + 1] = fmaxf(sy * di + b1s[f + 1], 0.0f);
        }
        __builtin_amdgcn_sched_barrier(0);  // wave-local LDS ops stay ordered
        float acc2 = 0.0f;
#pragma unroll
        for (int j = 0; j < 25; j++) {
            int k = q * 25 + j;
            acc2 += Hrow[w][k] * W2s[n16][k];
        }
        acc2 += __shfl_xor(acc2, 16);
        acc2 += __shfl_xor(acc2, 32);
        if (lane < 16) h2p[(size_t)node * CC + n16] = acc2 * di;
        __builtin_amdgcn_sched_barrier(0);
    }
}

// ---------- aggregation 2 + bias + log_softmax ----------
__global__ __launch_bounds__(256) void k_agg2(const float* __restrict__ h2p,
                                              const int* __restrict__ row_ptr,
                                              const int* __restrict__ deg,
                                              const int* __restrict__ csr_src,
                                              const float* __restrict__ dinv,
                                              const void* __restrict__ b2,
                                              void* __restrict__ out,
                                              const int* __restrict__ flags) {
    int tid = threadIdx.x;
    int n = tid & 15;
    int g = tid >> 4;
    int node = blockIdx.x * 16 + g;
    if (node >= NN) return;
    const int bf = flags[0];
    float a0 = h2p[(size_t)node * CC + n];
    float a1 = 0.f, a2 = 0.f, a3 = 0.f;
    int lo = row_ptr[node], hi = lo + deg[node];
    int e = lo;
    for (; e + 3 < hi; e += 4) {
        int s0 = csr_src[e], s1 = csr_src[e + 1], s2 = csr_src[e + 2], s3 = csr_src[e + 3];
        a0 += h2p[(size_t)s0 * CC + n];
        a1 += h2p[(size_t)s1 * CC + n];
        a2 += h2p[(size_t)s2 * CC + n];
        a3 += h2p[(size_t)s3 * CC + n];
    }
    for (; e < hi; e++) a0 += h2p[(size_t)csr_src[e] * CC + n];
    float acc = (a0 + a1) + (a2 + a3);
    float logit = acc * dinv[node] + ldf(b2, n, bf);
    float m = logit;
#pragma unroll
    for (int off = 1; off < 16; off <<= 1) m = fmaxf(m, __shfl_xor(m, off, 16));
    float ex = __expf(logit - m);
    float ssum = ex;
#pragma unroll
    for (int off = 1; off < 16; off <<= 1) ssum += __shfl_xor(ssum, off, 16);
    float r = logit - m - __logf(ssum);
    size_t oidx = (size_t)node * CC + n;
    if (bf) ((__hip_bfloat16*)out)[oidx] = __float2bfloat16(r);
    else    ((float*)out)[oidx] = r;
}

extern "C" void kernel_launch(void* const* d_in, const int* in_sizes, int n_in,
                              void* d_out, int out_size, void* d_ws, size_t ws_size,
                              hipStream_t stream) {
    const void* x     = d_in[0];
    const void* lin_W = d_in[1];
    const void* lin_b = d_in[2];
    const void* W1    = d_in[3];
    const void* b1    = d_in[4];
    const void* W2    = d_in[5];
    const void* b2    = d_in[6];
    const int*  ei    = (const int*)d_in[7];

    char* ws = (char*)d_ws;
    size_t off = 0;
    auto alloc = [&](size_t bytes) {
        off = (off + 255) & ~(size_t)255;
        void* p = ws + off;
        off += bytes;
        return p;
    };
    int*   flags   = (int*)alloc(2 * 4);
    int*   total   = (int*)alloc(4);
    int*   cnt     = (int*)alloc((size_t)NN * 4);   // becomes deg after scatter
    int*   row_ptr = (int*)alloc((size_t)NN * 4);
    int*   csr_src = (int*)alloc((size_t)EE * 4);
    float* dinv    = (float*)alloc((size_t)NN * 4);
    // H1: fp32 mode = bf16 [NN][320] (32 MB); bf16-input fallback = fp32 [NN][300]
    char*  H1      = (char*)alloc((size_t)NN * H1D * 4);
    unsigned short* H1p = (unsigned short*)alloc((size_t)NN * H2D * 2);
    float* h2p     = (float*)alloc((size_t)NN * CC * 4);
    unsigned short* Bt1 = (unsigned short*)alloc((size_t)384 * 1024 * 2);
    unsigned short* Bt2 = (unsigned short*)alloc((size_t)128 * 640 * 2);

    const int gE = (EE + 255) / 256;

    // Host-side dtype evidence: x as fp32 is exactly 100 MB.
    const bool surely_fp32 = (in_sizes != nullptr) && (in_sizes[0] >= 90000000);

    // init: sniff (+ weight prep when dtype is host-certain)
    k_init<<<surely_fp32 ? (1 + PREP_BLOCKS) : 1, 256, 0, stream>>>(
        (const unsigned short*)x, (const unsigned int*)ei, flags,
        (const float*)lin_W, (const float*)W1, Bt1, Bt2);
    if (!surely_fp32)
        k_prep_both<<<PREP_BLOCKS, 256, 0, stream>>>(
            (const float*)lin_W, (const float*)W1, Bt1, Bt2, flags);

    // CSR build: single cooperative kernel (zero+hist+scan+dinv+scatter);
    // fallback to 4-kernel chain if cooperative launch is rejected.
    {
        void* kargs[] = {(void*)&ei, (void*)&cnt, (void*)&row_ptr, (void*)&dinv,
                         (void*)&csr_src, (void*)&total, (void*)&flags};
        hipError_t err = hipLaunchCooperativeKernel((void*)k_csr_coop, dim3(1024), dim3(256),
                                                    kargs, 0, stream);
        if (err != hipSuccess) {
            (void)hipGetLastError();  // clear
            k_zero_cnt<<<GNB, 256, 0, stream>>>(cnt, total);
            k_hist<<<gE, 256, 0, stream>>>(ei, cnt, flags);
            k_scan_mb<<<GNB, 256, 0, stream>>>(cnt, row_ptr, dinv, total);
            k_scatter<<<gE, 256, 0, stream>>>(ei, row_ptr, cnt, csr_src, flags);
        }
    }

    // H1 = relu(x @ lin_W + lin_b) -> bf16 [.][320] (pad zeroed); single dispatch
    k_gemm_mfma_split<64, 4, true, false, true, true>
        <<<dim3(3, (NN + 63) / 64), 256, 0, stream>>>(
            (const float*)x, Bt1, (const float*)lin_b, nullptr, (unsigned short*)H1,
            NN, FIN, 512, H1D, 320, flags);
    if (!surely_fp32) {   // bf16-input fallback (early-exits in fp32 mode)
        dim3 grid((NN + 63) / 64, (H1D + 63) / 64);
        k_gemm<true, true, false, false><<<grid, 256, 0, stream>>>(
            x, lin_W, lin_b, nullptr, H1, NN, FIN, H1D, flags);
    }

    // H1p = (H1 @ W1) * dinv -> bf16 [.][100]
    k_gemm2_bf16a<<<(NN + 63) / 64, 256, 0, stream>>>(
        (const unsigned short*)H1, Bt2, dinv, H1p, NN, flags);
    if (!surely_fp32) {   // bf16-input fallback
        dim3 grid((NN + 63) / 64, (H2D + 63) / 64);
        k_gemm<false, false, true, true><<<grid, 256, 0, stream>>>(
            H1, W1, nullptr, dinv, H1p, NN, H1D, H2D, flags);
    }

    // h2p = relu(dinv*AGG(H1p)+b1) @ W2 * dinv
    k_agg1_fused<<<6144, 256, 0, stream>>>(H1p, row_ptr, cnt, csr_src, dinv, b1, W2, h2p, flags);
    // out = log_softmax(dinv * (gather-sum h2p) + b2)
    k_agg2<<<(NN + 15) / 16, 256, 0, stream>>>(h2p, row_ptr, cnt, csr_src, dinv, b2, d_out, flags);
}

// Round 13
// 413.844 us; speedup vs baseline: 1.6573x; 1.6573x over previous
//
#include <hip/hip_runtime.h>
#include <hip/hip_bf16.h>

#define NN 50000
#define EE 800000
#define FIN 500
#define H1D 300
#define H2D 100
#define CC 16
#define GNB 196          // (NN+255)/256
#define PREP_N1 196608   // 384*512
#define PREP_N2 40960    // 128*320
#define PREP_BLOCKS 928  // (PREP_N1+PREP_N2)/256

// ---------- dtype-flexible load helpers ----------
__device__ __forceinline__ float ldf(const void* p, size_t i, int isbf16) {
    return isbf16 ? __bfloat162float(((const __hip_bfloat16*)p)[i])
                  : ((const float*)p)[i];
}
__device__ __forceinline__ int ld_src(const int* ei, int e, int is64) {
    return is64 ? ei[2 * (size_t)e] : ei[e];
}
__device__ __forceinline__ int ld_dst(const int* ei, int e, int is64) {
    return is64 ? ei[2 * ((size_t)EE + e)] : ei[(size_t)EE + e];
}

// split fp32 -> hi/lo bf16 (hi+lo captures ~17 mantissa bits)
__device__ __forceinline__ void split2(float f, unsigned short& h, unsigned short& l) {
    __bf16 hb = (__bf16)f;
    float fh = (float)hb;
    __bf16 lb = (__bf16)(f - fh);
    h = __builtin_bit_cast(unsigned short, hb);
    l = __builtin_bit_cast(unsigned short, lb);
}

// unpack 2 packed bf16 to float2
__device__ __forceinline__ float2 bf2f2(unsigned int v) {
    float lo = __builtin_bit_cast(float, v << 16);
    float hi = __builtin_bit_cast(float, v & 0xffff0000u);
    return make_float2(lo, hi);
}

typedef __bf16 bf16x8 __attribute__((ext_vector_type(8)));
typedef float f32x4 __attribute__((ext_vector_type(4)));

// ---------- prep body ----------
__device__ __forceinline__ void prep_body(int idx, const float* linW, const float* W1,
                                          unsigned short* Bt1, unsigned short* Bt2) {
    if (idx < PREP_N1) {
        int n = idx >> 9, k = idx & 511;
        float v = (n < H1D && k < FIN) ? linW[(size_t)k * H1D + n] : 0.0f;
        unsigned short h, l;
        split2(v, h, l);
        Bt1[(size_t)n * 1024 + k] = h;
        Bt1[(size_t)n * 1024 + 512 + k] = l;
    } else if (idx < PREP_N1 + PREP_N2) {
        idx -= PREP_N1;
        int n = idx / 320, k = idx - n * 320;
        float v = (n < H2D && k < H1D) ? W1[(size_t)k * H2D + n] : 0.0f;
        unsigned short h, l;
        split2(v, h, l);
        Bt2[(size_t)n * 640 + k] = h;
        Bt2[(size_t)n * 640 + 320 + k] = l;
    }
}

// ---------- init: sniff (block 0) + zero cnt (blocks 1..GNB) + optional weight prep ----------
__global__ __launch_bounds__(256) void k_init(const unsigned short* __restrict__ xw,
                                              const unsigned int* __restrict__ ew,
                                              int* __restrict__ flags,
                                              int* __restrict__ cnt,
                                              int* __restrict__ total,
                                              const float* __restrict__ linW,
                                              const float* __restrict__ W1,
                                              unsigned short* __restrict__ Bt1,
                                              unsigned short* __restrict__ Bt2) {
    int b = blockIdx.x;
    if (b == 0) {
        __shared__ int c_sane, c_zero;
        if (threadIdx.x == 0) { c_sane = 0; c_zero = 0; }
        __syncthreads();
        int t = threadIdx.x;
        int sane = 0, zer = 0;
        for (int j = 0; j < 4; j++) {
            unsigned short w = xw[t * 4 + j];
            int ex = (w >> 7) & 0xFF;
            if (w == 0 || (ex >= 100 && ex <= 150)) sane++;
            if (ew[2 * (t * 4 + j) + 1] == 0u) zer++;
        }
        atomicAdd(&c_sane, sane);
        atomicAdd(&c_zero, zer);
        __syncthreads();
        if (threadIdx.x == 0) {
            flags[0] = (c_sane > 820) ? 1 : 0;
            flags[1] = (c_zero > 512) ? 1 : 0;
            total[0] = 0;
        }
    } else if (b <= GNB) {
        int i = (b - 1) * 256 + threadIdx.x;
        if (i < NN) cnt[i] = 0;
    } else {
        // only present when host is CERTAIN input is fp32 (grid extended)
        prep_body((b - GNB - 1) * 256 + threadIdx.x, linW, W1, Bt1, Bt2);
    }
}

// standalone prep for the uncertain-dtype path (flags-gated)
__global__ __launch_bounds__(256) void k_prep_both(const float* __restrict__ linW,
                                                   const float* __restrict__ W1,
                                                   unsigned short* __restrict__ Bt1,
                                                   unsigned short* __restrict__ Bt2,
                                                   const int* __restrict__ flags) {
    if (flags[0]) return;
    prep_body(blockIdx.x * 256 + threadIdx.x, linW, W1, Bt1, Bt2);
}

// ---------- CSR chain (4 kernels -- R7/R10-proven; cooperative version regressed
// 333us vs ~70us in R12: grid.sync across 8 non-coherent XCDs costs more than
// the 3 inter-kernel drains it removes) ----------
__global__ void k_hist(const int* __restrict__ ei, int* __restrict__ cnt,
                       const int* __restrict__ flags) {
    int e = blockIdx.x * blockDim.x + threadIdx.x;
    int is64 = flags[1];
    if (e < EE) {
        int d = ld_dst(ei, e, is64);
        if ((unsigned)d < NN) atomicAdd(&cnt[d], 1);
    }
}

__global__ __launch_bounds__(256) void k_scan_mb(int* __restrict__ cnt,
                                                 int* __restrict__ row_ptr,
                                                 float* __restrict__ dinv,
                                                 int* __restrict__ total) {
    int t = threadIdx.x;
    int i = blockIdx.x * 256 + t;
    int c = (i < NN) ? cnt[i] : 0;
    __shared__ int s[256];
    s[t] = c;
    __syncthreads();
    for (int off = 1; off < 256; off <<= 1) {
        int v = (t >= off) ? s[t - off] : 0;
        __syncthreads();
        s[t] += v;
        __syncthreads();
    }
    __shared__ int base;
    if (t == 255) base = atomicAdd(total, s[255]);
    __syncthreads();
    if (i < NN) {
        row_ptr[i] = base + s[t] - c;
        dinv[i] = rsqrtf((float)c + 1.0f);  // +1 self loop
        cnt[i] = 0;                          // scatter fill counter (ends = deg)
    }
}

__global__ void k_scatter(const int* __restrict__ ei, const int* __restrict__ row_ptr,
                          int* __restrict__ fill, int* __restrict__ csr_src,
                          const int* __restrict__ flags) {
    int e = blockIdx.x * blockDim.x + threadIdx.x;
    int is64 = flags[1];
    if (e < EE) {
        int s = ld_src(ei, e, is64);
        int d = ld_dst(ei, e, is64);
        if ((unsigned)d < NN) {
            int pos = row_ptr[d] + atomicAdd(&fill[d], 1);
            csr_src[pos] = s;
        }
    }
}

// ---------- bf16-input fallback tiled GEMM (runs only when flags[0]==1) ----------
template <bool A_DYN, bool RELU, bool SCALE, bool OUTBF>
__global__ __launch_bounds__(256) void k_gemm(const void* __restrict__ A,
                                              const void* __restrict__ B,
                                              const void* __restrict__ bias,
                                              const float* __restrict__ dinv,
                                              void* __restrict__ C,
                                              int M, int K, int Nn,
                                              const int* __restrict__ flags) {
    if (!flags[0]) return;
    __shared__ float As[16][68];
    __shared__ float Bs[16][68];
    const int bf = flags[0];
    const int tid = threadIdx.x;
    const int m0 = blockIdx.x * 64, n0 = blockIdx.y * 64;
    const int tx = tid & 15;
    const int ty = tid >> 4;
    float acc[4][4] = {};

    for (int kc = 0; kc < K; kc += 16) {
#pragma unroll
        for (int j = 0; j < 4; j++) {
            int idx = tid + j * 256;
            int kk = idx & 15, mm = idx >> 4;
            int gm = m0 + mm, gk = kc + kk;
            float v = 0.0f;
            if (gm < M && gk < K) {
                size_t o = (size_t)gm * K + gk;
                v = A_DYN ? ldf(A, o, bf) : ((const float*)A)[o];
            }
            As[kk][mm] = v;
        }
#pragma unroll
        for (int j = 0; j < 4; j++) {
            int idx = tid + j * 256;
            int nn = idx & 63, kk = idx >> 6;
            int gk = kc + kk, gn = n0 + nn;
            Bs[kk][nn] = (gk < K && gn < Nn) ? ldf(B, (size_t)gk * Nn + gn, bf) : 0.0f;
        }
        __syncthreads();
#pragma unroll
        for (int kk = 0; kk < 16; kk++) {
            float4 a4 = *(const float4*)&As[kk][ty * 4];
            float4 b4 = *(const float4*)&Bs[kk][tx * 4];
            float av[4] = {a4.x, a4.y, a4.z, a4.w};
            float bv[4] = {b4.x, b4.y, b4.z, b4.w};
#pragma unroll
            for (int i = 0; i < 4; i++)
#pragma unroll
                for (int j = 0; j < 4; j++) acc[i][j] += av[i] * bv[j];
        }
        __syncthreads();
    }

#pragma unroll
    for (int i = 0; i < 4; i++) {
        int m = m0 + ty * 4 + i;
        if (m >= M) continue;
        float sc = SCALE ? dinv[m] : 1.0f;
#pragma unroll
        for (int j = 0; j < 4; j++) {
            int n = n0 + tx * 4 + j;
            if (n >= Nn) continue;
            float v = acc[i][j];
            if (bias) v += ldf(bias, n, bf);
            if (SCALE) v *= sc;
            if (RELU) v = fmaxf(v, 0.0f);
            if (OUTBF) ((__hip_bfloat16*)C)[(size_t)m * Nn + n] = __float2bfloat16(v);
            else       ((float*)C)[(size_t)m * Nn + n] = v;
        }
    }
}

// ---------- split-bf16 MFMA GEMM1 (R7/R10-proven K-loop; single dispatch) ----------
template <int BM, int WN, bool RELU, bool SCALE, bool HAS_BIAS, bool OUTBF>
__global__ __launch_bounds__(256) void k_gemm_mfma_split(const float* __restrict__ A,
                                                         const unsigned short* __restrict__ Bt,
                                                         const float* __restrict__ bias,
                                                         const float* __restrict__ dinv,
                                                         void* __restrict__ C,
                                                         int M, int K, int Kp, int Nn, int NnS,
                                                         const int* __restrict__ flags) {
    if (flags[0]) return;
    constexpr int WM = 4 / WN;
    constexpr int FM = BM / WM / 16;
    constexpr int FN = 128 / WN / 16;
    constexpr int NA = BM / 32;
    __shared__ unsigned short As_hi[BM * 32], As_lo[BM * 32];
    __shared__ unsigned short Bs_hi[4096], Bs_lo[4096];
    const int tid = threadIdx.x;
    const int nbx = gridDim.x;
    const int Wt = nbx * gridDim.y;
    const int li = blockIdx.x + nbx * blockIdx.y;
    const int q8 = Wt >> 3, r8 = Wt & 7;
    const int xk = li & 7, xj = li >> 3;
    const int wid = (xk < r8 ? xk * (q8 + 1) : r8 * (q8 + 1) + (xk - r8) * q8) + xj;
    const int n0 = (wid % nbx) * 128;
    const int m0 = (wid / nbx) * BM;
    const int w = tid >> 6, l = tid & 63;
    const int wm = (w / WN) * (BM / WM);
    const int wn = (w % WN) * (128 / WN);
    const int lr = l & 15, ls = l >> 4;
    f32x4 acc[FM][FN] = {};

    float4 stA[NA];
    uint4  stB0, stB1, stB2, stB3;

#define LOAD_TILE(kc_)                                                              \
    {                                                                               \
        int kc = (kc_);                                                             \
        _Pragma("unroll")                                                           \
        for (int j = 0; j < NA; j++) {                                              \
            int c = tid + j * 256;                                                  \
            int r = c >> 3, q = c & 7;                                              \
            int gm = m0 + r, gk = kc + q * 4;                                       \
            stA[j] = (gm < M && gk < K) ? *(const float4*)(A + (size_t)gm * K + gk) \
                                        : make_float4(0.f, 0.f, 0.f, 0.f);          \
        }                                                                           \
        {                                                                           \
            int c, r, q, gn;                                                        \
            c = tid;       r = c >> 2; q = c & 3; gn = n0 + r;                      \
            stB0 = *(const uint4*)(Bt + (size_t)gn * (2 * Kp) + kc + q * 8);        \
            c = tid + 256; r = c >> 2; q = c & 3; gn = n0 + r;                      \
            stB1 = *(const uint4*)(Bt + (size_t)gn * (2 * Kp) + kc + q * 8);        \
            c = tid;       r = c >> 2; q = c & 3; gn = n0 + r;                      \
            stB2 = *(const uint4*)(Bt + (size_t)gn * (2 * Kp) + Kp + kc + q * 8);   \
            c = tid + 256; r = c >> 2; q = c & 3; gn = n0 + r;                      \
            stB3 = *(const uint4*)(Bt + (size_t)gn * (2 * Kp) + Kp + kc + q * 8);   \
        }                                                                           \
    }

#define WRITE_TILE()                                                                \
    {                                                                               \
        _Pragma("unroll")                                                           \
        for (int j = 0; j < NA; j++) {                                              \
            int c = tid + j * 256;                                                  \
            int r = c >> 3, q = c & 7;                                              \
            unsigned short h0,h1,h2,h3,l0,l1,l2,l3;                                 \
            split2(stA[j].x, h0, l0); split2(stA[j].y, h1, l1);                     \
            split2(stA[j].z, h2, l2); split2(stA[j].w, h3, l3);                     \
            int waddr = r * 64 + (((q >> 1) ^ ((r >> 1) & 3)) << 4) + ((q & 1) << 3); \
            *(ushort4*)((char*)As_hi + waddr) = make_ushort4(h0, h1, h2, h3);       \
            *(ushort4*)((char*)As_lo + waddr) = make_ushort4(l0, l1, l2, l3);       \
        }                                                                           \
        {                                                                           \
            int c, r, q, waddr;                                                     \
            c = tid;       r = c >> 2; q = c & 3; waddr = r * 64 + ((q ^ ((r >> 1) & 3)) << 4); \
            *(uint4*)((char*)Bs_hi + waddr) = stB0;                                 \
            c = tid + 256; r = c >> 2; q = c & 3; waddr = r * 64 + ((q ^ ((r >> 1) & 3)) << 4); \
            *(uint4*)((char*)Bs_hi + waddr) = stB1;                                 \
            c = tid;       r = c >> 2; q = c & 3; waddr = r * 64 + ((q ^ ((r >> 1) & 3)) << 4); \
            *(uint4*)((char*)Bs_lo + waddr) = stB2;                                 \
            c = tid + 256; r = c >> 2; q = c & 3; waddr = r * 64 + ((q ^ ((r >> 1) & 3)) << 4); \
            *(uint4*)((char*)Bs_lo + waddr) = stB3;                                 \
        }                                                                           \
    }

    const int nsteps = (K + 31) / 32;
    LOAD_TILE(0);
    for (int kt = 0; kt < nsteps; kt++) {
        WRITE_TILE();
        __syncthreads();
        if (kt + 1 < nsteps) LOAD_TILE((kt + 1) * 32);
        bf16x8 ah[FM], al[FM], bh[FN], bl[FN];
#pragma unroll
        for (int fm = 0; fm < FM; fm++) {
            int rr = wm + fm * 16 + lr;
            int addr = rr * 64 + ((ls ^ ((rr >> 1) & 3)) << 4);
            ah[fm] = *(const bf16x8*)((const char*)As_hi + addr);
            al[fm] = *(const bf16x8*)((const char*)As_lo + addr);
        }
#pragma unroll
        for (int fn = 0; fn < FN; fn++) {
            int cc2 = wn + fn * 16 + lr;
            int addr = cc2 * 64 + ((ls ^ ((cc2 >> 1) & 3)) << 4);
            bh[fn] = *(const bf16x8*)((const char*)Bs_hi + addr);
            bl[fn] = *(const bf16x8*)((const char*)Bs_lo + addr);
        }
#pragma unroll
        for (int fm = 0; fm < FM; fm++)
#pragma unroll
            for (int fn = 0; fn < FN; fn++) {
                acc[fm][fn] = __builtin_amdgcn_mfma_f32_16x16x32_bf16(ah[fm], bh[fn], acc[fm][fn], 0, 0, 0);
                acc[fm][fn] = __builtin_amdgcn_mfma_f32_16x16x32_bf16(ah[fm], bl[fn], acc[fm][fn], 0, 0, 0);
                acc[fm][fn] = __builtin_amdgcn_mfma_f32_16x16x32_bf16(al[fm], bh[fn], acc[fm][fn], 0, 0, 0);
            }
        __syncthreads();
    }
#undef LOAD_TILE
#undef WRITE_TILE

    // epilogue: C/D layout col=lane&15, row=(lane>>4)*4+reg [m89-verified]
#pragma unroll
    for (int fm = 0; fm < FM; fm++) {
#pragma unroll
        for (int j = 0; j < 4; j++) {
            int m = m0 + wm + fm * 16 + ls * 4 + j;
            if (m >= M) continue;
            float sc = SCALE ? dinv[m] : 1.0f;
#pragma unroll
            for (int fn = 0; fn < FN; fn++) {
                int n = n0 + wn + fn * 16 + lr;
                if (OUTBF) {
                    if (n >= NnS) continue;
                    float v = 0.0f;
                    if (n < Nn) {
                        v = acc[fm][fn][j];
                        if (HAS_BIAS) v += bias[n];
                        if (SCALE) v *= sc;
                        if (RELU) v = fmaxf(v, 0.0f);
                    }
                    ((__hip_bfloat16*)C)[(size_t)m * NnS + n] = __float2bfloat16(v);
                } else {
                    if (n >= Nn) continue;
                    float v = acc[fm][fn][j];
                    if (HAS_BIAS) v += bias[n];
                    if (SCALE) v *= sc;
                    if (RELU) v = fmaxf(v, 0.0f);
                    ((float*)C)[(size_t)m * Nn + n] = v;
                }
            }
        }
    }
}

// ---------- GEMM2 with bf16 A: H1p = (H1bf[M][320] @ W1) * dinv -> bf16 [M][100] ----------
__global__ __launch_bounds__(256) void k_gemm2_bf16a(const unsigned short* __restrict__ A,
                                                     const unsigned short* __restrict__ Bt,
                                                     const float* __restrict__ dinv,
                                                     unsigned short* __restrict__ C,
                                                     int M, const int* __restrict__ flags) {
    if (flags[0]) return;
    constexpr int Kp = 320;
    __shared__ unsigned short As[64 * 32];
    __shared__ unsigned short Bs_hi[4096], Bs_lo[4096];
    const int tid = threadIdx.x;
    const int Wt = gridDim.x;
    const int li = blockIdx.x;
    const int q8 = Wt >> 3, r8 = Wt & 7;
    const int xk = li & 7, xj = li >> 3;
    const int wid = (xk < r8 ? xk * (q8 + 1) : r8 * (q8 + 1) + (xk - r8) * q8) + xj;
    const int m0 = wid * 64;
    const int w = tid >> 6, l = tid & 63;
    const int wn = w * 32;
    const int lr = l & 15, ls = l >> 4;
    f32x4 acc[4][2] = {};

    uint4 stA, stB0, stB1, stB2, stB3;

#define LOAD_T2(kc_)                                                                \
    {                                                                               \
        int kc = (kc_);                                                             \
        {                                                                           \
            int r = tid >> 2, q = tid & 3;                                          \
            int gm = m0 + r;                                                        \
            stA = (gm < M) ? *(const uint4*)(A + (size_t)gm * Kp + kc + q * 8)      \
                           : make_uint4(0u, 0u, 0u, 0u);                            \
        }                                                                           \
        {                                                                           \
            int c, r, q, gn;                                                        \
            c = tid;       r = c >> 2; q = c & 3; gn = r;                           \
            stB0 = *(const uint4*)(Bt + (size_t)gn * (2 * Kp) + kc + q * 8);        \
            c = tid + 256; r = c >> 2; q = c & 3; gn = r;                           \
            stB1 = *(const uint4*)(Bt + (size_t)gn * (2 * Kp) + kc + q * 8);        \
            c = tid;       r = c >> 2; q = c & 3; gn = r;                           \
            stB2 = *(const uint4*)(Bt + (size_t)gn * (2 * Kp) + Kp + kc + q * 8);   \
            c = tid + 256; r = c >> 2; q = c & 3; gn = r;                           \
            stB3 = *(const uint4*)(Bt + (size_t)gn * (2 * Kp) + Kp + kc + q * 8);   \
        }                                                                           \
    }

#define WRITE_T2()                                                                  \
    {                                                                               \
        {                                                                           \
            int r = tid >> 2, q = tid & 3;                                          \
            int waddr = r * 64 + ((q ^ ((r >> 1) & 3)) << 4);                       \
            *(uint4*)((char*)As + waddr) = stA;                                     \
        }                                                                           \
        {                                                                           \
            int c, r, q, waddr;                                                     \
            c = tid;       r = c >> 2; q = c & 3; waddr = r * 64 + ((q ^ ((r >> 1) & 3)) << 4); \
            *(uint4*)((char*)Bs_hi + waddr) = stB0;                                 \
            c = tid + 256; r = c >> 2; q = c & 3; waddr = r * 64 + ((q ^ ((r >> 1) & 3)) << 4); \
            *(uint4*)((char*)Bs_hi + waddr) = stB1;                                 \
            c = tid;       r = c >> 2; q = c & 3; waddr = r * 64 + ((q ^ ((r >> 1) & 3)) << 4); \
            *(uint4*)((char*)Bs_lo + waddr) = stB2;                                 \
            c = tid + 256; r = c >> 2; q = c & 3; waddr = r * 64 + ((q ^ ((r >> 1) & 3)) << 4); \
            *(uint4*)((char*)Bs_lo + waddr) = stB3;                                 \
        }                                                                           \
    }

    const int nsteps = Kp / 32;  // 10
    LOAD_T2(0);
    for (int kt = 0; kt < nsteps; kt++) {
        WRITE_T2();
        __syncthreads();
        if (kt + 1 < nsteps) LOAD_T2((kt + 1) * 32);
        bf16x8 ah[4], bh[2], bl[2];
#pragma unroll
        for (int fm = 0; fm < 4; fm++) {
            int rr = fm * 16 + lr;
            int addr = rr * 64 + ((ls ^ ((rr >> 1) & 3)) << 4);
            ah[fm] = *(const bf16x8*)((const char*)As + addr);
        }
#pragma unroll
        for (int fn = 0; fn < 2; fn++) {
            int cc2 = wn + fn * 16 + lr;
            int addr = cc2 * 64 + ((ls ^ ((cc2 >> 1) & 3)) << 4);
            bh[fn] = *(const bf16x8*)((const char*)Bs_hi + addr);
            bl[fn] = *(const bf16x8*)((const char*)Bs_lo + addr);
        }
#pragma unroll
        for (int fm = 0; fm < 4; fm++)
#pragma unroll
            for (int fn = 0; fn < 2; fn++) {
                acc[fm][fn] = __builtin_amdgcn_mfma_f32_16x16x32_bf16(ah[fm], bh[fn], acc[fm][fn], 0, 0, 0);
                acc[fm][fn] = __builtin_amdgcn_mfma_f32_16x16x32_bf16(ah[fm], bl[fn], acc[fm][fn], 0, 0, 0);
            }
        __syncthreads();
    }
#undef LOAD_T2
#undef WRITE_T2

#pragma unroll
    for (int fm = 0; fm < 4; fm++) {
#pragma unroll
        for (int j = 0; j < 4; j++) {
            int m = m0 + fm * 16 + ls * 4 + j;
            if (m >= M) continue;
            float sc = dinv[m];
#pragma unroll
            for (int fn = 0; fn < 2; fn++) {
                int n = wn + fn * 16 + lr;
                if (n >= H2D) continue;
                ((__hip_bfloat16*)C)[(size_t)m * H2D + n] = __float2bfloat16(acc[fm][fn][j] * sc);
            }
        }
    }
}

// ---------- agg1 + gemm3 fused ----------
__global__ __launch_bounds__(256) void k_agg1_fused(const unsigned short* __restrict__ h1p_bf,
                                                    const int* __restrict__ row_ptr,
                                                    const int* __restrict__ deg,
                                                    const int* __restrict__ csr_src,
                                                    const float* __restrict__ dinv,
                                                    const void* __restrict__ b1,
                                                    const void* __restrict__ W2,
                                                    float* __restrict__ h2p,
                                                    const int* __restrict__ flags) {
    __shared__ float W2s[16][105];
    __shared__ float b1s[H2D];
    __shared__ float Hrow[4][H2D];
    const int bf = flags[0];
    const int tid = threadIdx.x;
    for (int i = tid; i < H2D * CC; i += 256) {
        int k = i >> 4, n = i & 15;
        W2s[n][k] = ldf(W2, i, bf);
    }
    for (int i = tid; i < H2D; i += 256) b1s[i] = ldf(b1, i, bf);
    __syncthreads();

    const int w = tid >> 6, lane = tid & 63;
    const int q = lane >> 4, n16 = lane & 15;
    const unsigned int* rows = (const unsigned int*)h1p_bf;  // 50 uints/node
    for (int node = blockIdx.x * 4 + w; node < NN; node += gridDim.x * 4) {
        float di = dinv[node];
        if (lane < 50) {
            float2 s = bf2f2(rows[(size_t)node * 50 + lane]);  // self loop
            float a0x = s.x, a0y = s.y;
            float a1x = 0.f, a1y = 0.f, a2x = 0.f, a2y = 0.f, a3x = 0.f, a3y = 0.f;
            int lo = row_ptr[node], hi = lo + deg[node];
            int e = lo;
            for (; e + 3 < hi; e += 4) {
                int s0 = csr_src[e], s1 = csr_src[e + 1], s2 = csr_src[e + 2], s3 = csr_src[e + 3];
                float2 v0 = bf2f2(rows[(size_t)s0 * 50 + lane]);
                float2 v1 = bf2f2(rows[(size_t)s1 * 50 + lane]);
                float2 v2 = bf2f2(rows[(size_t)s2 * 50 + lane]);
                float2 v3 = bf2f2(rows[(size_t)s3 * 50 + lane]);
                a0x += v0.x; a0y += v0.y;
                a1x += v1.x; a1y += v1.y;
                a2x += v2.x; a2y += v2.y;
                a3x += v3.x; a3y += v3.y;
            }
            for (; e < hi; e++) {
                float2 v = bf2f2(rows[(size_t)csr_src[e] * 50 + lane]);
                a0x += v.x; a0y += v.y;
            }
            float sx = (a0x + a1x) + (a2x + a3x);
            float sy = (a0y + a1y) + (a2y + a3y);
            int f = lane * 2;
            Hrow[w][f]     = fmaxf(sx * di + b1s[f], 0.0f);
            Hrow[w][f + 1] = fmaxf(sy * di + b1s[f + 1], 0.0f);
        }
        __builtin_amdgcn_sched_barrier(0);  // wave-local LDS ops stay ordered
        float acc2 = 0.0f;
#pragma unroll
        for (int j = 0; j < 25; j++) {
            int k = q * 25 + j;
            acc2 += Hrow[w][k] * W2s[n16][k];
        }
        acc2 += __shfl_xor(acc2, 16);
        acc2 += __shfl_xor(acc2, 32);
        if (lane < 16) h2p[(size_t)node * CC + n16] = acc2 * di;
        __builtin_amdgcn_sched_barrier(0);
    }
}

// ---------- aggregation 2 + bias + log_softmax ----------
__global__ __launch_bounds__(256) void k_agg2(const float* __restrict__ h2p,
                                              const int* __restrict__ row_ptr,
                                              const int* __restrict__ deg,
                                              const int* __restrict__ csr_src,
                                              const float* __restrict__ dinv,
                                              const void* __restrict__ b2,
                                              void* __restrict__ out,
                                              const int* __restrict__ flags) {
    int tid = threadIdx.x;
    int n = tid & 15;
    int g = tid >> 4;
    int node = blockIdx.x * 16 + g;
    if (node >= NN) return;
    const int bf = flags[0];
    float a0 = h2p[(size_t)node * CC + n];
    float a1 = 0.f, a2 = 0.f, a3 = 0.f;
    int lo = row_ptr[node], hi = lo + deg[node];
    int e = lo;
    for (; e + 3 < hi; e += 4) {
        int s0 = csr_src[e], s1 = csr_src[e + 1], s2 = csr_src[e + 2], s3 = csr_src[e + 3];
        a0 += h2p[(size_t)s0 * CC + n];
        a1 += h2p[(size_t)s1 * CC + n];
        a2 += h2p[(size_t)s2 * CC + n];
        a3 += h2p[(size_t)s3 * CC + n];
    }
    for (; e < hi; e++) a0 += h2p[(size_t)csr_src[e] * CC + n];
    float acc = (a0 + a1) + (a2 + a3);
    float logit = acc * dinv[node] + ldf(b2, n, bf);
    float m = logit;
#pragma unroll
    for (int off = 1; off < 16; off <<= 1) m = fmaxf(m, __shfl_xor(m, off, 16));
    float ex = __expf(logit - m);
    float ssum = ex;
#pragma unroll
    for (int off = 1; off < 16; off <<= 1) ssum += __shfl_xor(ssum, off, 16);
    float r = logit - m - __logf(ssum);
    size_t oidx = (size_t)node * CC + n;
    if (bf) ((__hip_bfloat16*)out)[oidx] = __float2bfloat16(r);
    else    ((float*)out)[oidx] = r;
}

extern "C" void kernel_launch(void* const* d_in, const int* in_sizes, int n_in,
                              void* d_out, int out_size, void* d_ws, size_t ws_size,
                              hipStream_t stream) {
    const void* x     = d_in[0];
    const void* lin_W = d_in[1];
    const void* lin_b = d_in[2];
    const void* W1    = d_in[3];
    const void* b1    = d_in[4];
    const void* W2    = d_in[5];
    const void* b2    = d_in[6];
    const int*  ei    = (const int*)d_in[7];

    char* ws = (char*)d_ws;
    size_t off = 0;
    auto alloc = [&](size_t bytes) {
        off = (off + 255) & ~(size_t)255;
        void* p = ws + off;
        off += bytes;
        return p;
    };
    int*   flags   = (int*)alloc(2 * 4);
    int*   total   = (int*)alloc(4);
    int*   cnt     = (int*)alloc((size_t)NN * 4);   // becomes deg after scatter
    int*   row_ptr = (int*)alloc((size_t)NN * 4);
    int*   csr_src = (int*)alloc((size_t)EE * 4);
    float* dinv    = (float*)alloc((size_t)NN * 4);
    // H1: fp32 mode = bf16 [NN][320] (32 MB); bf16-input fallback = fp32 [NN][300]
    char*  H1      = (char*)alloc((size_t)NN * H1D * 4);
    unsigned short* H1p = (unsigned short*)alloc((size_t)NN * H2D * 2);
    float* h2p     = (float*)alloc((size_t)NN * CC * 4);
    unsigned short* Bt1 = (unsigned short*)alloc((size_t)384 * 1024 * 2);
    unsigned short* Bt2 = (unsigned short*)alloc((size_t)128 * 640 * 2);

    const int gE = (EE + 255) / 256;

    // Host-side dtype evidence: x as fp32 is exactly 100 MB.
    const bool surely_fp32 = (in_sizes != nullptr) && (in_sizes[0] >= 90000000);

    // init: sniff + zero cnt (+ weight prep when dtype is host-certain)
    k_init<<<surely_fp32 ? (GNB + 1 + PREP_BLOCKS) : (GNB + 1), 256, 0, stream>>>(
        (const unsigned short*)x, (const unsigned int*)ei, flags, cnt, total,
        (const float*)lin_W, (const float*)W1, Bt1, Bt2);
    if (!surely_fp32)
        k_prep_both<<<PREP_BLOCKS, 256, 0, stream>>>(
            (const float*)lin_W, (const float*)W1, Bt1, Bt2, flags);

    // CSR + degrees (proven 4-kernel chain)
    k_hist<<<gE, 256, 0, stream>>>(ei, cnt, flags);
    k_scan_mb<<<GNB, 256, 0, stream>>>(cnt, row_ptr, dinv, total);
    k_scatter<<<gE, 256, 0, stream>>>(ei, row_ptr, cnt, csr_src, flags);

    // H1 = relu(x @ lin_W + lin_b) -> bf16 [.][320] (pad zeroed); single dispatch
    k_gemm_mfma_split<64, 4, true, false, true, true>
        <<<dim3(3, (NN + 63) / 64), 256, 0, stream>>>(
            (const float*)x, Bt1, (const float*)lin_b, nullptr, (unsigned short*)H1,
            NN, FIN, 512, H1D, 320, flags);
    if (!surely_fp32) {   // bf16-input fallback (early-exits in fp32 mode)
        dim3 grid((NN + 63) / 64, (H1D + 63) / 64);
        k_gemm<true, true, false, false><<<grid, 256, 0, stream>>>(
            x, lin_W, lin_b, nullptr, H1, NN, FIN, H1D, flags);
    }

    // H1p = (H1 @ W1) * dinv -> bf16 [.][100]
    k_gemm2_bf16a<<<(NN + 63) / 64, 256, 0, stream>>>(
        (const unsigned short*)H1, Bt2, dinv, H1p, NN, flags);
    if (!surely_fp32) {   // bf16-input fallback
        dim3 grid((NN + 63) / 64, (H2D + 63) / 64);
        k_gemm<false, false, true, true><<<grid, 256, 0, stream>>>(
            H1, W1, nullptr, dinv, H1p, NN, H1D, H2D, flags);
    }

    // h2p = relu(dinv*AGG(H1p)+b1) @ W2 * dinv
    k_agg1_fused<<<6144, 256, 0, stream>>>(H1p, row_ptr, cnt, csr_src, dinv, b1, W2, h2p, flags);
    // out = log_softmax(dinv * (gather-sum h2p) + b2)
    k_agg2<<<(NN + 15) / 16, 256, 0, stream>>>(h2p, row_ptr, cnt, csr_src, dinv, b2, d_out, flags);
}

// Round 14
// 406.518 us; speedup vs baseline: 1.6872x; 1.0180x over previous
//
#include <hip/hip_runtime.h>
#include <hip/hip_bf16.h>

#define NN 50000
#define EE 800000
#define FIN 500
#define H1D 300
#define H2D 100
#define CC 16
#define GNB 196          // (NN+255)/256
#define PREP_N1 196608   // 384*512
#define PREP_N2 40960    // 128*320
#define PREP_BLOCKS 928  // (PREP_N1+PREP_N2)/256

// ---------- dtype-flexible load helpers ----------
__device__ __forceinline__ float ldf(const void* p, size_t i, int isbf16) {
    return isbf16 ? __bfloat162float(((const __hip_bfloat16*)p)[i])
                  : ((const float*)p)[i];
}
__device__ __forceinline__ int ld_src(const int* ei, int e, int is64) {
    return is64 ? ei[2 * (size_t)e] : ei[e];
}
__device__ __forceinline__ int ld_dst(const int* ei, int e, int is64) {
    return is64 ? ei[2 * ((size_t)EE + e)] : ei[(size_t)EE + e];
}

// split fp32 -> hi/lo bf16 (hi+lo captures ~17 mantissa bits)
__device__ __forceinline__ void split2(float f, unsigned short& h, unsigned short& l) {
    __bf16 hb = (__bf16)f;
    float fh = (float)hb;
    __bf16 lb = (__bf16)(f - fh);
    h = __builtin_bit_cast(unsigned short, hb);
    l = __builtin_bit_cast(unsigned short, lb);
}
__device__ __forceinline__ unsigned short f2bf(float f) {
    return __builtin_bit_cast(unsigned short, (__bf16)f);
}

// unpack 2 packed bf16 to float2
__device__ __forceinline__ float2 bf2f2(unsigned int v) {
    float lo = __builtin_bit_cast(float, v << 16);
    float hi = __builtin_bit_cast(float, v & 0xffff0000u);
    return make_float2(lo, hi);
}

typedef __bf16 bf16x8 __attribute__((ext_vector_type(8)));
typedef float f32x4 __attribute__((ext_vector_type(4)));

// ---------- prep body ----------
__device__ __forceinline__ void prep_body(int idx, const float* linW, const float* W1,
                                          unsigned short* Bt1, unsigned short* Bt2) {
    if (idx < PREP_N1) {
        int n = idx >> 9, k = idx & 511;
        float v = (n < H1D && k < FIN) ? linW[(size_t)k * H1D + n] : 0.0f;
        unsigned short h, l;
        split2(v, h, l);
        Bt1[(size_t)n * 1024 + k] = h;
        Bt1[(size_t)n * 1024 + 512 + k] = l;
    } else if (idx < PREP_N1 + PREP_N2) {
        idx -= PREP_N1;
        int n = idx / 320, k = idx - n * 320;
        float v = (n < H2D && k < H1D) ? W1[(size_t)k * H2D + n] : 0.0f;
        unsigned short h, l;
        split2(v, h, l);
        Bt2[(size_t)n * 640 + k] = h;
        Bt2[(size_t)n * 640 + 320 + k] = l;
    }
}

// ---------- init: sniff (block 0) + zero cnt (blocks 1..GNB) + optional weight prep ----------
__global__ __launch_bounds__(256) void k_init(const unsigned short* __restrict__ xw,
                                              const unsigned int* __restrict__ ew,
                                              int* __restrict__ flags,
                                              int* __restrict__ cnt,
                                              int* __restrict__ total,
                                              const float* __restrict__ linW,
                                              const float* __restrict__ W1,
                                              unsigned short* __restrict__ Bt1,
                                              unsigned short* __restrict__ Bt2) {
    int b = blockIdx.x;
    if (b == 0) {
        __shared__ int c_sane, c_zero;
        if (threadIdx.x == 0) { c_sane = 0; c_zero = 0; }
        __syncthreads();
        int t = threadIdx.x;
        int sane = 0, zer = 0;
        for (int j = 0; j < 4; j++) {
            unsigned short w = xw[t * 4 + j];
            int ex = (w >> 7) & 0xFF;
            if (w == 0 || (ex >= 100 && ex <= 150)) sane++;
            if (ew[2 * (t * 4 + j) + 1] == 0u) zer++;
        }
        atomicAdd(&c_sane, sane);
        atomicAdd(&c_zero, zer);
        __syncthreads();
        if (threadIdx.x == 0) {
            flags[0] = (c_sane > 820) ? 1 : 0;
            flags[1] = (c_zero > 512) ? 1 : 0;
            total[0] = 0;
        }
    } else if (b <= GNB) {
        int i = (b - 1) * 256 + threadIdx.x;
        if (i < NN) cnt[i] = 0;
    } else {
        // only present when host is CERTAIN input is fp32 (grid extended)
        prep_body((b - GNB - 1) * 256 + threadIdx.x, linW, W1, Bt1, Bt2);
    }
}

// standalone prep for the uncertain-dtype path (flags-gated)
__global__ __launch_bounds__(256) void k_prep_both(const float* __restrict__ linW,
                                                   const float* __restrict__ W1,
                                                   unsigned short* __restrict__ Bt1,
                                                   unsigned short* __restrict__ Bt2,
                                                   const int* __restrict__ flags) {
    if (flags[0]) return;
    prep_body(blockIdx.x * 256 + threadIdx.x, linW, W1, Bt1, Bt2);
}

// ---------- CSR chain (4 kernels -- proven; cooperative version regressed R12) ----------
__global__ void k_hist(const int* __restrict__ ei, int* __restrict__ cnt,
                       const int* __restrict__ flags) {
    int e = blockIdx.x * blockDim.x + threadIdx.x;
    int is64 = flags[1];
    if (e < EE) {
        int d = ld_dst(ei, e, is64);
        if ((unsigned)d < NN) atomicAdd(&cnt[d], 1);
    }
}

__global__ __launch_bounds__(256) void k_scan_mb(int* __restrict__ cnt,
                                                 int* __restrict__ row_ptr,
                                                 float* __restrict__ dinv,
                                                 int* __restrict__ total) {
    int t = threadIdx.x;
    int i = blockIdx.x * 256 + t;
    int c = (i < NN) ? cnt[i] : 0;
    __shared__ int s[256];
    s[t] = c;
    __syncthreads();
    for (int off = 1; off < 256; off <<= 1) {
        int v = (t >= off) ? s[t - off] : 0;
        __syncthreads();
        s[t] += v;
        __syncthreads();
    }
    __shared__ int base;
    if (t == 255) base = atomicAdd(total, s[255]);
    __syncthreads();
    if (i < NN) {
        row_ptr[i] = base + s[t] - c;
        dinv[i] = rsqrtf((float)c + 1.0f);  // +1 self loop
        cnt[i] = 0;                          // scatter fill counter (ends = deg)
    }
}

__global__ void k_scatter(const int* __restrict__ ei, const int* __restrict__ row_ptr,
                          int* __restrict__ fill, int* __restrict__ csr_src,
                          const int* __restrict__ flags) {
    int e = blockIdx.x * blockDim.x + threadIdx.x;
    int is64 = flags[1];
    if (e < EE) {
        int s = ld_src(ei, e, is64);
        int d = ld_dst(ei, e, is64);
        if ((unsigned)d < NN) {
            int pos = row_ptr[d] + atomicAdd(&fill[d], 1);
            csr_src[pos] = s;
        }
    }
}

// ---------- bf16-input fallback tiled GEMM (runs only when flags[0]==1) ----------
template <bool A_DYN, bool RELU, bool SCALE, bool OUTBF>
__global__ __launch_bounds__(256) void k_gemm(const void* __restrict__ A,
                                              const void* __restrict__ B,
                                              const void* __restrict__ bias,
                                              const float* __restrict__ dinv,
                                              void* __restrict__ C,
                                              int M, int K, int Nn,
                                              const int* __restrict__ flags) {
    if (!flags[0]) return;
    __shared__ float As[16][68];
    __shared__ float Bs[16][68];
    const int bf = flags[0];
    const int tid = threadIdx.x;
    const int m0 = blockIdx.x * 64, n0 = blockIdx.y * 64;
    const int tx = tid & 15;
    const int ty = tid >> 4;
    float acc[4][4] = {};

    for (int kc = 0; kc < K; kc += 16) {
#pragma unroll
        for (int j = 0; j < 4; j++) {
            int idx = tid + j * 256;
            int kk = idx & 15, mm = idx >> 4;
            int gm = m0 + mm, gk = kc + kk;
            float v = 0.0f;
            if (gm < M && gk < K) {
                size_t o = (size_t)gm * K + gk;
                v = A_DYN ? ldf(A, o, bf) : ((const float*)A)[o];
            }
            As[kk][mm] = v;
        }
#pragma unroll
        for (int j = 0; j < 4; j++) {
            int idx = tid + j * 256;
            int nn = idx & 63, kk = idx >> 6;
            int gk = kc + kk, gn = n0 + nn;
            Bs[kk][nn] = (gk < K && gn < Nn) ? ldf(B, (size_t)gk * Nn + gn, bf) : 0.0f;
        }
        __syncthreads();
#pragma unroll
        for (int kk = 0; kk < 16; kk++) {
            float4 a4 = *(const float4*)&As[kk][ty * 4];
            float4 b4 = *(const float4*)&Bs[kk][tx * 4];
            float av[4] = {a4.x, a4.y, a4.z, a4.w};
            float bv[4] = {b4.x, b4.y, b4.z, b4.w};
#pragma unroll
            for (int i = 0; i < 4; i++)
#pragma unroll
                for (int j = 0; j < 4; j++) acc[i][j] += av[i] * bv[j];
        }
        __syncthreads();
    }

#pragma unroll
    for (int i = 0; i < 4; i++) {
        int m = m0 + ty * 4 + i;
        if (m >= M) continue;
        float sc = SCALE ? dinv[m] : 1.0f;
#pragma unroll
        for (int j = 0; j < 4; j++) {
            int n = n0 + tx * 4 + j;
            if (n >= Nn) continue;
            float v = acc[i][j];
            if (bias) v += ldf(bias, n, bf);
            if (SCALE) v *= sc;
            if (RELU) v = fmaxf(v, 0.0f);
            if (OUTBF) ((__hip_bfloat16*)C)[(size_t)m * Nn + n] = __float2bfloat16(v);
            else       ((float*)C)[(size_t)m * Nn + n] = v;
        }
    }
}

// ---------- MFMA GEMM1: C = bf16(A) @ (Bhi+Blo) -- 2 MFMAs per B pair ----------
// R14: A rounded to plain bf16 in staging (same 2^-9 error class as the already-
// accepted bf16 H1/H1p quantization); A-lo LDS plane deleted (LDS 24->20KB,
// MFMA count -33%, split VALU halved). B keeps 17-bit hi/lo precision.
template <int BM, int WN, bool RELU, bool SCALE, bool HAS_BIAS, bool OUTBF>
__global__ __launch_bounds__(256) void k_gemm_mfma_split(const float* __restrict__ A,
                                                         const unsigned short* __restrict__ Bt,
                                                         const float* __restrict__ bias,
                                                         const float* __restrict__ dinv,
                                                         void* __restrict__ C,
                                                         int M, int K, int Kp, int Nn, int NnS,
                                                         const int* __restrict__ flags) {
    if (flags[0]) return;
    constexpr int WM = 4 / WN;
    constexpr int FM = BM / WM / 16;
    constexpr int FN = 128 / WN / 16;
    constexpr int NA = BM / 32;
    __shared__ unsigned short As_hi[BM * 32];
    __shared__ unsigned short Bs_hi[4096], Bs_lo[4096];
    const int tid = threadIdx.x;
    const int nbx = gridDim.x;
    const int Wt = nbx * gridDim.y;
    const int li = blockIdx.x + nbx * blockIdx.y;
    const int q8 = Wt >> 3, r8 = Wt & 7;
    const int xk = li & 7, xj = li >> 3;
    const int wid = (xk < r8 ? xk * (q8 + 1) : r8 * (q8 + 1) + (xk - r8) * q8) + xj;
    const int n0 = (wid % nbx) * 128;
    const int m0 = (wid / nbx) * BM;
    const int w = tid >> 6, l = tid & 63;
    const int wm = (w / WN) * (BM / WM);
    const int wn = (w % WN) * (128 / WN);
    const int lr = l & 15, ls = l >> 4;
    f32x4 acc[FM][FN] = {};

    float4 stA[NA];
    uint4  stB0, stB1, stB2, stB3;

#define LOAD_TILE(kc_)                                                              \
    {                                                                               \
        int kc = (kc_);                                                             \
        _Pragma("unroll")                                                           \
        for (int j = 0; j < NA; j++) {                                              \
            int c = tid + j * 256;                                                  \
            int r = c >> 3, q = c & 7;                                              \
            int gm = m0 + r, gk = kc + q * 4;                                       \
            stA[j] = (gm < M && gk < K) ? *(const float4*)(A + (size_t)gm * K + gk) \
                                        : make_float4(0.f, 0.f, 0.f, 0.f);          \
        }                                                                           \
        {                                                                           \
            int c, r, q, gn;                                                        \
            c = tid;       r = c >> 2; q = c & 3; gn = n0 + r;                      \
            stB0 = *(const uint4*)(Bt + (size_t)gn * (2 * Kp) + kc + q * 8);        \
            c = tid + 256; r = c >> 2; q = c & 3; gn = n0 + r;                      \
            stB1 = *(const uint4*)(Bt + (size_t)gn * (2 * Kp) + kc + q * 8);        \
            c = tid;       r = c >> 2; q = c & 3; gn = n0 + r;                      \
            stB2 = *(const uint4*)(Bt + (size_t)gn * (2 * Kp) + Kp + kc + q * 8);   \
            c = tid + 256; r = c >> 2; q = c & 3; gn = n0 + r;                      \
            stB3 = *(const uint4*)(Bt + (size_t)gn * (2 * Kp) + Kp + kc + q * 8);   \
        }                                                                           \
    }

#define WRITE_TILE()                                                                \
    {                                                                               \
        _Pragma("unroll")                                                           \
        for (int j = 0; j < NA; j++) {                                              \
            int c = tid + j * 256;                                                  \
            int r = c >> 3, q = c & 7;                                              \
            ushort4 hv = make_ushort4(f2bf(stA[j].x), f2bf(stA[j].y),               \
                                      f2bf(stA[j].z), f2bf(stA[j].w));              \
            int waddr = r * 64 + (((q >> 1) ^ ((r >> 1) & 3)) << 4) + ((q & 1) << 3); \
            *(ushort4*)((char*)As_hi + waddr) = hv;                                 \
        }                                                                           \
        {                                                                           \
            int c, r, q, waddr;                                                     \
            c = tid;       r = c >> 2; q = c & 3; waddr = r * 64 + ((q ^ ((r >> 1) & 3)) << 4); \
            *(uint4*)((char*)Bs_hi + waddr) = stB0;                                 \
            c = tid + 256; r = c >> 2; q = c & 3; waddr = r * 64 + ((q ^ ((r >> 1) & 3)) << 4); \
            *(uint4*)((char*)Bs_hi + waddr) = stB1;                                 \
            c = tid;       r = c >> 2; q = c & 3; waddr = r * 64 + ((q ^ ((r >> 1) & 3)) << 4); \
            *(uint4*)((char*)Bs_lo + waddr) = stB2;                                 \
            c = tid + 256; r = c >> 2; q = c & 3; waddr = r * 64 + ((q ^ ((r >> 1) & 3)) << 4); \
            *(uint4*)((char*)Bs_lo + waddr) = stB3;                                 \
        }                                                                           \
    }

    const int nsteps = (K + 31) / 32;
    LOAD_TILE(0);
    for (int kt = 0; kt < nsteps; kt++) {
        WRITE_TILE();
        __syncthreads();
        if (kt + 1 < nsteps) LOAD_TILE((kt + 1) * 32);
        bf16x8 ah[FM], bh[FN], bl[FN];
#pragma unroll
        for (int fm = 0; fm < FM; fm++) {
            int rr = wm + fm * 16 + lr;
            int addr = rr * 64 + ((ls ^ ((rr >> 1) & 3)) << 4);
            ah[fm] = *(const bf16x8*)((const char*)As_hi + addr);
        }
#pragma unroll
        for (int fn = 0; fn < FN; fn++) {
            int cc2 = wn + fn * 16 + lr;
            int addr = cc2 * 64 + ((ls ^ ((cc2 >> 1) & 3)) << 4);
            bh[fn] = *(const bf16x8*)((const char*)Bs_hi + addr);
            bl[fn] = *(const bf16x8*)((const char*)Bs_lo + addr);
        }
#pragma unroll
        for (int fm = 0; fm < FM; fm++)
#pragma unroll
            for (int fn = 0; fn < FN; fn++) {
                acc[fm][fn] = __builtin_amdgcn_mfma_f32_16x16x32_bf16(ah[fm], bh[fn], acc[fm][fn], 0, 0, 0);
                acc[fm][fn] = __builtin_amdgcn_mfma_f32_16x16x32_bf16(ah[fm], bl[fn], acc[fm][fn], 0, 0, 0);
            }
        __syncthreads();
    }
#undef LOAD_TILE
#undef WRITE_TILE

    // epilogue: C/D layout col=lane&15, row=(lane>>4)*4+reg [m89-verified]
#pragma unroll
    for (int fm = 0; fm < FM; fm++) {
#pragma unroll
        for (int j = 0; j < 4; j++) {
            int m = m0 + wm + fm * 16 + ls * 4 + j;
            if (m >= M) continue;
            float sc = SCALE ? dinv[m] : 1.0f;
#pragma unroll
            for (int fn = 0; fn < FN; fn++) {
                int n = n0 + wn + fn * 16 + lr;
                if (OUTBF) {
                    if (n >= NnS) continue;
                    float v = 0.0f;
                    if (n < Nn) {
                        v = acc[fm][fn][j];
                        if (HAS_BIAS) v += bias[n];
                        if (SCALE) v *= sc;
                        if (RELU) v = fmaxf(v, 0.0f);
                    }
                    ((__hip_bfloat16*)C)[(size_t)m * NnS + n] = __float2bfloat16(v);
                } else {
                    if (n >= Nn) continue;
                    float v = acc[fm][fn][j];
                    if (HAS_BIAS) v += bias[n];
                    if (SCALE) v *= sc;
                    if (RELU) v = fmaxf(v, 0.0f);
                    ((float*)C)[(size_t)m * Nn + n] = v;
                }
            }
        }
    }
}

// ---------- GEMM2 with bf16 A: H1p = (H1bf[M][320] @ W1) * dinv -> bf16 [M][100] ----------
__global__ __launch_bounds__(256) void k_gemm2_bf16a(const unsigned short* __restrict__ A,
                                                     const unsigned short* __restrict__ Bt,
                                                     const float* __restrict__ dinv,
                                                     unsigned short* __restrict__ C,
                                                     int M, const int* __restrict__ flags) {
    if (flags[0]) return;
    constexpr int Kp = 320;
    __shared__ unsigned short As[64 * 32];
    __shared__ unsigned short Bs_hi[4096], Bs_lo[4096];
    const int tid = threadIdx.x;
    const int Wt = gridDim.x;
    const int li = blockIdx.x;
    const int q8 = Wt >> 3, r8 = Wt & 7;
    const int xk = li & 7, xj = li >> 3;
    const int wid = (xk < r8 ? xk * (q8 + 1) : r8 * (q8 + 1) + (xk - r8) * q8) + xj;
    const int m0 = wid * 64;
    const int w = tid >> 6, l = tid & 63;
    const int wn = w * 32;
    const int lr = l & 15, ls = l >> 4;
    f32x4 acc[4][2] = {};

    uint4 stA, stB0, stB1, stB2, stB3;

#define LOAD_T2(kc_)                                                                \
    {                                                                               \
        int kc = (kc_);                                                             \
        {                                                                           \
            int r = tid >> 2, q = tid & 3;                                          \
            int gm = m0 + r;                                                        \
            stA = (gm < M) ? *(const uint4*)(A + (size_t)gm * Kp + kc + q * 8)      \
                           : make_uint4(0u, 0u, 0u, 0u);                            \
        }                                                                           \
        {                                                                           \
            int c, r, q, gn;                                                        \
            c = tid;       r = c >> 2; q = c & 3; gn = r;                           \
            stB0 = *(const uint4*)(Bt + (size_t)gn * (2 * Kp) + kc + q * 8);        \
            c = tid + 256; r = c >> 2; q = c & 3; gn = r;                           \
            stB1 = *(const uint4*)(Bt + (size_t)gn * (2 * Kp) + kc + q * 8);        \
            c = tid;       r = c >> 2; q = c & 3; gn = r;                           \
            stB2 = *(const uint4*)(Bt + (size_t)gn * (2 * Kp) + Kp + kc + q * 8);   \
            c = tid + 256; r = c >> 2; q = c & 3; gn = r;                           \
            stB3 = *(const uint4*)(Bt + (size_t)gn * (2 * Kp) + Kp + kc + q * 8);   \
        }                                                                           \
    }

#define WRITE_T2()                                                                  \
    {                                                                               \
        {                                                                           \
            int r = tid >> 2, q = tid & 3;                                          \
            int waddr = r * 64 + ((q ^ ((r >> 1) & 3)) << 4);                       \
            *(uint4*)((char*)As + waddr) = stA;                                     \
        }                                                                           \
        {                                                                           \
            int c, r, q, waddr;                                                     \
            c = tid;       r = c >> 2; q = c & 3; waddr = r * 64 + ((q ^ ((r >> 1) & 3)) << 4); \
            *(uint4*)((char*)Bs_hi + waddr) = stB0;                                 \
            c = tid + 256; r = c >> 2; q = c & 3; waddr = r * 64 + ((q ^ ((r >> 1) & 3)) << 4); \
            *(uint4*)((char*)Bs_hi + waddr) = stB1;                                 \
            c = tid;       r = c >> 2; q = c & 3; waddr = r * 64 + ((q ^ ((r >> 1) & 3)) << 4); \
            *(uint4*)((char*)Bs_lo + waddr) = stB2;                                 \
            c = tid + 256; r = c >> 2; q = c & 3; waddr = r * 64 + ((q ^ ((r >> 1) & 3)) << 4); \
            *(uint4*)((char*)Bs_lo + waddr) = stB3;                                 \
        }                                                                           \
    }

    const int nsteps = Kp / 32;  // 10
    LOAD_T2(0);
    for (int kt = 0; kt < nsteps; kt++) {
        WRITE_T2();
        __syncthreads();
        if (kt + 1 < nsteps) LOAD_T2((kt + 1) * 32);
        bf16x8 ah[4], bh[2], bl[2];
#pragma unroll
        for (int fm = 0; fm < 4; fm++) {
            int rr = fm * 16 + lr;
            int addr = rr * 64 + ((ls ^ ((rr >> 1) & 3)) << 4);
            ah[fm] = *(const bf16x8*)((const char*)As + addr);
        }
#pragma unroll
        for (int fn = 0; fn < 2; fn++) {
            int cc2 = wn + fn * 16 + lr;
            int addr = cc2 * 64 + ((ls ^ ((cc2 >> 1) & 3)) << 4);
            bh[fn] = *(const bf16x8*)((const char*)Bs_hi + addr);
            bl[fn] = *(const bf16x8*)((const char*)Bs_lo + addr);
        }
#pragma unroll
        for (int fm = 0; fm < 4; fm++)
#pragma unroll
            for (int fn = 0; fn < 2; fn++) {
                acc[fm][fn] = __builtin_amdgcn_mfma_f32_16x16x32_bf16(ah[fm], bh[fn], acc[fm][fn], 0, 0, 0);
                acc[fm][fn] = __builtin_amdgcn_mfma_f32_16x16x32_bf16(ah[fm], bl[fn], acc[fm][fn], 0, 0, 0);
            }
        __syncthreads();
    }
#undef LOAD_T2
#undef WRITE_T2

#pragma unroll
    for (int fm = 0; fm < 4; fm++) {
#pragma unroll
        for (int j = 0; j < 4; j++) {
            int m = m0 + fm * 16 + ls * 4 + j;
            if (m >= M) continue;
            float sc = dinv[m];
#pragma unroll
            for (int fn = 0; fn < 2; fn++) {
                int n = wn + fn * 16 + lr;
                if (n >= H2D) continue;
                ((__hip_bfloat16*)C)[(size_t)m * H2D + n] = __float2bfloat16(acc[fm][fn][j] * sc);
            }
        }
    }
}

// ---------- agg1 + gemm3 fused ----------
__global__ __launch_bounds__(256) void k_agg1_fused(const unsigned short* __restrict__ h1p_bf,
                                                    const int* __restrict__ row_ptr,
                                                    const int* __restrict__ deg,
                                                    const int* __restrict__ csr_src,
                                                    const float* __restrict__ dinv,
                                                    const void* __restrict__ b1,
                                                    const void* __restrict__ W2,
                                                    float* __restrict__ h2p,
                                                    const int* __restrict__ flags) {
    __shared__ float W2s[16][105];
    __shared__ float b1s[H2D];
    __shared__ float Hrow[4][H2D];
    const int bf = flags[0];
    const int tid = threadIdx.x;
    for (int i = tid; i < H2D * CC; i += 256) {
        int k = i >> 4, n = i & 15;
        W2s[n][k] = ldf(W2, i, bf);
    }
    for (int i = tid; i < H2D; i += 256) b1s[i] = ldf(b1, i, bf);
    __syncthreads();

    const int w = tid >> 6, lane = tid & 63;
    const int q = lane >> 4, n16 = lane & 15;
    const unsigned int* rows = (const unsigned int*)h1p_bf;  // 50 uints/node
    for (int node = blockIdx.x * 4 + w; node < NN; node += gridDim.x * 4) {
        float di = dinv[node];
        if (lane < 50) {
            float2 s = bf2f2(rows[(size_t)node * 50 + lane]);  // self loop
            float a0x = s.x, a0y = s.y;
            float a1x = 0.f, a1y = 0.f, a2x = 0.f, a2y = 0.f, a3x = 0.f, a3y = 0.f;
            int lo = row_ptr[node], hi = lo + deg[node];
            int e = lo;
            for (; e + 3 < hi; e += 4) {
                int s0 = csr_src[e], s1 = csr_src[e + 1], s2 = csr_src[e + 2], s3 = csr_src[e + 3];
                float2 v0 = bf2f2(rows[(size_t)s0 * 50 + lane]);
                float2 v1 = bf2f2(rows[(size_t)s1 * 50 + lane]);
                float2 v2 = bf2f2(rows[(size_t)s2 * 50 + lane]);
                float2 v3 = bf2f2(rows[(size_t)s3 * 50 + lane]);
                a0x += v0.x; a0y += v0.y;
                a1x += v1.x; a1y += v1.y;
                a2x += v2.x; a2y += v2.y;
                a3x += v3.x; a3y += v3.y;
            }
            for (; e < hi; e++) {
                float2 v = bf2f2(rows[(size_t)csr_src[e] * 50 + lane]);
                a0x += v.x; a0y += v.y;
            }
            float sx = (a0x + a1x) + (a2x + a3x);
            float sy = (a0y + a1y) + (a2y + a3y);
            int f = lane * 2;
            Hrow[w][f]     = fmaxf(sx * di + b1s[f], 0.0f);
            Hrow[w][f + 1] = fmaxf(sy * di + b1s[f + 1], 0.0f);
        }
        __builtin_amdgcn_sched_barrier(0);  // wave-local LDS ops stay ordered
        float acc2 = 0.0f;
#pragma unroll
        for (int j = 0; j < 25; j++) {
            int k = q * 25 + j;
            acc2 += Hrow[w][k] * W2s[n16][k];
        }
        acc2 += __shfl_xor(acc2, 16);
        acc2 += __shfl_xor(acc2, 32);
        if (lane < 16) h2p[(size_t)node * CC + n16] = acc2 * di;
        __builtin_amdgcn_sched_barrier(0);
    }
}

// ---------- aggregation 2 + bias + log_softmax ----------
__global__ __launch_bounds__(256) void k_agg2(const float* __restrict__ h2p,
                                              const int* __restrict__ row_ptr,
                                              const int* __restrict__ deg,
                                              const int* __restrict__ csr_src,
                                              const float* __restrict__ dinv,
                                              const void* __restrict__ b2,
                                              void* __restrict__ out,
                                              const int* __restrict__ flags) {
    int tid = threadIdx.x;
    int n = tid & 15;
    int g = tid >> 4;
    int node = blockIdx.x * 16 + g;
    if (node >= NN) return;
    const int bf = flags[0];
    float a0 = h2p[(size_t)node * CC + n];
    float a1 = 0.f, a2 = 0.f, a3 = 0.f;
    int lo = row_ptr[node], hi = lo + deg[node];
    int e = lo;
    for (; e + 3 < hi; e += 4) {
        int s0 = csr_src[e], s1 = csr_src[e + 1], s2 = csr_src[e + 2], s3 = csr_src[e + 3];
        a0 += h2p[(size_t)s0 * CC + n];
        a1 += h2p[(size_t)s1 * CC + n];
        a2 += h2p[(size_t)s2 * CC + n];
        a3 += h2p[(size_t)s3 * CC + n];
    }
    for (; e < hi; e++) a0 += h2p[(size_t)csr_src[e] * CC + n];
    float acc = (a0 + a1) + (a2 + a3);
    float logit = acc * dinv[node] + ldf(b2, n, bf);
    float m = logit;
#pragma unroll
    for (int off = 1; off < 16; off <<= 1) m = fmaxf(m, __shfl_xor(m, off, 16));
    float ex = __expf(logit - m);
    float ssum = ex;
#pragma unroll
    for (int off = 1; off < 16; off <<= 1) ssum += __shfl_xor(ssum, off, 16);
    float r = logit - m - __logf(ssum);
    size_t oidx = (size_t)node * CC + n;
    if (bf) ((__hip_bfloat16*)out)[oidx] = __float2bfloat16(r);
    else    ((float*)out)[oidx] = r;
}

extern "C" void kernel_launch(void* const* d_in, const int* in_sizes, int n_in,
                              void* d_out, int out_size, void* d_ws, size_t ws_size,
                              hipStream_t stream) {
    const void* x     = d_in[0];
    const void* lin_W = d_in[1];
    const void* lin_b = d_in[2];
    const void* W1    = d_in[3];
    const void* b1    = d_in[4];
    const void* W2    = d_in[5];
    const void* b2    = d_in[6];
    const int*  ei    = (const int*)d_in[7];

    char* ws = (char*)d_ws;
    size_t off = 0;
    auto alloc = [&](size_t bytes) {
        off = (off + 255) & ~(size_t)255;
        void* p = ws + off;
        off += bytes;
        return p;
    };
    int*   flags   = (int*)alloc(2 * 4);
    int*   total   = (int*)alloc(4);
    int*   cnt     = (int*)alloc((size_t)NN * 4);   // becomes deg after scatter
    int*   row_ptr = (int*)alloc((size_t)NN * 4);
    int*   csr_src = (int*)alloc((size_t)EE * 4);
    float* dinv    = (float*)alloc((size_t)NN * 4);
    // H1: fp32 mode = bf16 [NN][320] (32 MB); bf16-input fallback = fp32 [NN][300]
    char*  H1      = (char*)alloc((size_t)NN * H1D * 4);
    unsigned short* H1p = (unsigned short*)alloc((size_t)NN * H2D * 2);
    float* h2p     = (float*)alloc((size_t)NN * CC * 4);
    unsigned short* Bt1 = (unsigned short*)alloc((size_t)384 * 1024 * 2);
    unsigned short* Bt2 = (unsigned short*)alloc((size_t)128 * 640 * 2);

    const int gE = (EE + 255) / 256;

    // Host-side dtype evidence: x as fp32 is exactly 100 MB.
    const bool surely_fp32 = (in_sizes != nullptr) && (in_sizes[0] >= 90000000);

    // init: sniff + zero cnt (+ weight prep when dtype is host-certain)
    k_init<<<surely_fp32 ? (GNB + 1 + PREP_BLOCKS) : (GNB + 1), 256, 0, stream>>>(
        (const unsigned short*)x, (const unsigned int*)ei, flags, cnt, total,
        (const float*)lin_W, (const float*)W1, Bt1, Bt2);
    if (!surely_fp32)
        k_prep_both<<<PREP_BLOCKS, 256, 0, stream>>>(
            (const float*)lin_W, (const float*)W1, Bt1, Bt2, flags);

    // CSR + degrees (proven 4-kernel chain)
    k_hist<<<gE, 256, 0, stream>>>(ei, cnt, flags);
    k_scan_mb<<<GNB, 256, 0, stream>>>(cnt, row_ptr, dinv, total);
    k_scatter<<<gE, 256, 0, stream>>>(ei, row_ptr, cnt, csr_src, flags);

    // H1 = relu(bf16(x) @ lin_W + lin_b) -> bf16 [.][320] (pad zeroed)
    k_gemm_mfma_split<64, 4, true, false, true, true>
        <<<dim3(3, (NN + 63) / 64), 256, 0, stream>>>(
            (const float*)x, Bt1, (const float*)lin_b, nullptr, (unsigned short*)H1,
            NN, FIN, 512, H1D, 320, flags);
    if (!surely_fp32) {   // bf16-input fallback (early-exits in fp32 mode)
        dim3 grid((NN + 63) / 64, (H1D + 63) / 64);
        k_gemm<true, true, false, false><<<grid, 256, 0, stream>>>(
            x, lin_W, lin_b, nullptr, H1, NN, FIN, H1D, flags);
    }

    // H1p = (H1 @ W1) * dinv -> bf16 [.][100]
    k_gemm2_bf16a<<<(NN + 63) / 64, 256, 0, stream>>>(
        (const unsigned short*)H1, Bt2, dinv, H1p, NN, flags);
    if (!surely_fp32) {   // bf16-input fallback
        dim3 grid((NN + 63) / 64, (H2D + 63) / 64);
        k_gemm<false, false, true, true><<<grid, 256, 0, stream>>>(
            H1, W1, nullptr, dinv, H1p, NN, H1D, H2D, flags);
    }

    // h2p = relu(dinv*AGG(H1p)+b1) @ W2 * dinv
    k_agg1_fused<<<6144, 256, 0, stream>>>(H1p, row_ptr, cnt, csr_src, dinv, b1, W2, h2p, flags);
    // out = log_softmax(dinv * (gather-sum h2p) + b2)
    k_agg2<<<(NN + 15) / 16, 256, 0, stream>>>(h2p, row_ptr, cnt, csr_src, dinv, b2, d_out, flags);
}